// Round 9
// baseline (1459.611 us; speedup 1.0000x reference)
//
#include <hip/hip_runtime.h>

#define EDIM 1024
#define NHEADS 16
#define HDIM 64
#define TSEQ 1024
#define NBATCH 2
#define MROWS 2048
#define FFDIM 4096
#define NLAYERS 8
#define VOCAB 32000
#define QKVN 3072
#define SC2 0.18033688011112042f   /* 0.125 * log2(e) */

typedef __attribute__((ext_vector_type(4))) float f32x4;
typedef __attribute__((ext_vector_type(8))) short short8;

__device__ __forceinline__ unsigned short f2bf(float f) {
    union { float f; unsigned u; } v; v.f = f;
    unsigned r = v.u + 0x7fffu + ((v.u >> 16) & 1u);
    return (unsigned short)(r >> 16);
}

__device__ __forceinline__ f32x4 mfma_bf16(short8 a, short8 b, f32x4 c) {
    return __builtin_amdgcn_mfma_f32_16x16x32_bf16(a, b, c, 0, 0, 0);
}

// async global->LDS, 16B per lane; LDS dest = wave-uniform base + lane*16
__device__ __forceinline__ void gload16(const unsigned short* g, unsigned short* l) {
    __builtin_amdgcn_global_load_lds(
        (const __attribute__((address_space(1))) unsigned int*)g,
        (__attribute__((address_space(3))) unsigned int*)l, 16, 0, 0);
}

// ---------------- LN core ----------------
__device__ __forceinline__ void ln_store(
    f32x4 v, int tid, const float* __restrict__ sc, const float* __restrict__ bi,
    unsigned short* __restrict__ hrow)
{
    float sum = v[0] + v[1] + v[2] + v[3];
    float sq = v[0]*v[0] + v[1]*v[1] + v[2]*v[2] + v[3]*v[3];
    #pragma unroll
    for (int m = 1; m <= 32; m <<= 1) { sum += __shfl_xor(sum, m); sq += __shfl_xor(sq, m); }
    __shared__ float sh[8];
    int w = tid >> 6;
    if ((tid & 63) == 0) { sh[w] = sum; sh[4 + w] = sq; }
    __syncthreads();
    sum = sh[0] + sh[1] + sh[2] + sh[3];
    sq  = sh[4] + sh[5] + sh[6] + sh[7];
    float mu = sum * (1.0f / EDIM);
    float inv = rsqrtf(sq * (1.0f / EDIM) - mu * mu + 1e-5f);
    int c = tid * 4;
    unsigned o0 = (unsigned)f2bf((v[0] - mu) * inv * sc[c + 0] + bi[c + 0])
                | ((unsigned)f2bf((v[1] - mu) * inv * sc[c + 1] + bi[c + 1]) << 16);
    unsigned o1 = (unsigned)f2bf((v[2] - mu) * inv * sc[c + 2] + bi[c + 2])
                | ((unsigned)f2bf((v[3] - mu) * inv * sc[c + 3] + bi[c + 3]) << 16);
    unsigned* hp = (unsigned*)(hrow + c);
    hp[0] = o0; hp[1] = o1;
}

// ---------------- embedding + first LN fused ----------------
__global__ __launch_bounds__(256) void embed_ln_kernel(
    const int* __restrict__ idx, const float* __restrict__ tok,
    const float* __restrict__ pos, float* __restrict__ x,
    const float* __restrict__ sc, const float* __restrict__ bi,
    unsigned short* __restrict__ h)
{
    int row = blockIdx.x, tid = threadIdx.x;
    int t = row & (TSEQ - 1);
    int tokid = idx[row];
    int c = tid * 4;
    f32x4 a = *(const f32x4*)(tok + (size_t)tokid * EDIM + c);
    f32x4 b = *(const f32x4*)(pos + (size_t)t * EDIM + c);
    f32x4 v = a + b;
    *(f32x4*)(x + (size_t)row * EDIM + c) = v;
    ln_store(v, tid, sc, bi, h + (size_t)row * EDIM);
}

// fused: x += bias + sum_kz part;  h = LN(x)
template<int KZ>
__global__ __launch_bounds__(256) void reduce_ln_kernel(
    const float* __restrict__ part, const float* __restrict__ bias,
    float* __restrict__ x, const float* __restrict__ sc,
    const float* __restrict__ bi, unsigned short* __restrict__ h)
{
    int row = blockIdx.x, tid = threadIdx.x;
    int c = tid * 4;
    f32x4 s = *(const f32x4*)(x + (size_t)row * EDIM + c);
    s += *(const f32x4*)(bias + c);
    #pragma unroll
    for (int kz = 0; kz < KZ; ++kz)
        s += *(const f32x4*)(part + ((size_t)kz * MROWS + row) * EDIM + c);
    *(f32x4*)(x + (size_t)row * EDIM + c) = s;
    ln_store(s, tid, sc, bi, h + (size_t)row * EDIM);
}

// ---------------- weight convert+transpose tile (64x64), LDS passed in ----------
__device__ __forceinline__ void conv_tile(
    unsigned short* __restrict__ Tb,   // >= 64*72 shorts
    const float* __restrict__ W, unsigned short* __restrict__ WT,
    int Kdim, int Ndim, int k0, int n0, int tid)
{
    int r = tid >> 4, c4 = (tid & 15) * 4;
    #pragma unroll
    for (int i = 0; i < 4; ++i) {
        f32x4 v = *(const f32x4*)(W + (size_t)(k0 + r + 16 * i) * Ndim + n0 + c4);
        Tb[(c4 + 0) * 72 + r + 16 * i] = f2bf(v[0]);
        Tb[(c4 + 1) * 72 + r + 16 * i] = f2bf(v[1]);
        Tb[(c4 + 2) * 72 + r + 16 * i] = f2bf(v[2]);
        Tb[(c4 + 3) * 72 + r + 16 * i] = f2bf(v[3]);
    }
    __syncthreads();
    int nr = tid >> 2, kc = (tid & 3) * 16;
    short8 o0 = *(const short8*)&Tb[nr * 72 + kc];
    short8 o1 = *(const short8*)&Tb[nr * 72 + kc + 8];
    *(short8*)(WT + (size_t)(n0 + nr) * Kdim + k0 + kc)     = o0;
    *(short8*)(WT + (size_t)(n0 + nr) * Kdim + k0 + kc + 8) = o1;
}

// conv dispatcher over one layer's 6 weights; t in [0, 3072)
__device__ __forceinline__ void wconv_layer_body(
    unsigned short* Tb, int t, int tid,
    const float* Wq, const float* Wk, const float* Wv, const float* Wo,
    const float* W1, const float* W2,
    unsigned short* qkvT, unsigned short* woT,
    unsigned short* w1T, unsigned short* w2T)
{
    if (t < 768) {
        int wsel = t >> 8, tt = t & 255;
        const float* src = wsel == 0 ? Wq : (wsel == 1 ? Wk : Wv);
        conv_tile(Tb, src, qkvT + (size_t)wsel * EDIM * EDIM, EDIM, EDIM,
                  (tt & 15) * 64, (tt >> 4) * 64, tid);
    } else if (t < 1024) {
        int tt = t - 768;
        conv_tile(Tb, Wo, woT, EDIM, EDIM, (tt & 15) * 64, (tt >> 4) * 64, tid);
    } else if (t < 2048) {
        int tt = t - 1024;
        conv_tile(Tb, W1, w1T, EDIM, FFDIM, (tt & 15) * 64, (tt >> 4) * 64, tid);
    } else {
        int tt = t - 2048;
        conv_tile(Tb, W2, w2T, FFDIM, EDIM, (tt >> 4) * 64, (tt & 15) * 64, tid);
    }
}

__global__ __launch_bounds__(256) void wconv_layer_kernel(
    const float* __restrict__ Wq, const float* __restrict__ Wk,
    const float* __restrict__ Wv, const float* __restrict__ Wo,
    const float* __restrict__ W1, const float* __restrict__ W2,
    unsigned short* __restrict__ qkvT, unsigned short* __restrict__ woT,
    unsigned short* __restrict__ w1T, unsigned short* __restrict__ w2T)
{
    __shared__ __align__(16) unsigned short Tb[64 * 72];
    wconv_layer_body(Tb, blockIdx.x, threadIdx.x, Wq, Wk, Wv, Wo, W1, W2,
                     qkvT, woT, w1T, w2T);
}

__global__ __launch_bounds__(256) void wconv_kernel(
    const float* __restrict__ W, unsigned short* __restrict__ WT, int Kdim, int Ndim)
{
    __shared__ __align__(16) unsigned short Tb[64 * 72];
    conv_tile(Tb, W, WT, Kdim, Ndim, blockIdx.x * 64, blockIdx.y * 64, threadIdx.x);
}

// ---------------- narrow GEMM body: block 128x128, 4 waves, BK=64, XOR-swizzle ----
// EPI 0: ->bf16   4: partial f32 (split-K)
template<int EPI>
__device__ __forceinline__ void gemm128_body(
    unsigned short* SMEM,   // >= 16384 shorts (A 8192 | B 8192)
    const unsigned short* __restrict__ A, const unsigned short* __restrict__ WT,
    float* __restrict__ Cf, unsigned short* __restrict__ Cb,
    int Ndim, int Kdim, int ntiles, int nwg, int kspan, int bid, int kz)
{
    unsigned short* A_lds = SMEM;
    unsigned short* B_lds = SMEM + 8192;
    int tid = threadIdx.x;
    int q8 = nwg >> 3;
    int swz = (bid & 7) * q8 + (bid >> 3);
    int bm0 = (swz / ntiles) * 128, bn0 = (swz % ntiles) * 128;
    int lane = tid & 63, w = tid >> 6;
    int wr = w >> 1, wc = w & 1;
    int r16 = lane & 15, cc = lane >> 4;
    int lrow = lane >> 3;
    int lcol = ((lane & 7) ^ lrow) * 8;
    int sw = r16 & 7;

    f32x4 acc[4][4];
    #pragma unroll
    for (int m = 0; m < 4; ++m)
        #pragma unroll
        for (int n = 0; n < 4; ++n) acc[m][n] = {0.f, 0.f, 0.f, 0.f};

    int kbeg = kz * kspan, kend = kbeg + kspan;
    for (int k0 = kbeg; k0 < kend; k0 += 64) {
        #pragma unroll
        for (int i = 0; i < 4; ++i) {
            int c = i * 4 + w;
            gload16(A + (size_t)(bm0 + c * 8 + lrow) * Kdim + k0 + lcol, A_lds + c * 512);
            gload16(WT + (size_t)(bn0 + c * 8 + lrow) * Kdim + k0 + lcol, B_lds + c * 512);
        }
        __syncthreads();
        #pragma unroll
        for (int kh = 0; kh < 2; ++kh) {
            short8 af[4], bfr[4];
            #pragma unroll
            for (int m = 0; m < 4; ++m)
                af[m] = *(const short8*)&A_lds[(wr * 64 + m * 16 + r16) * 64 + ((kh * 4 + cc) ^ sw) * 8];
            #pragma unroll
            for (int n = 0; n < 4; ++n)
                bfr[n] = *(const short8*)&B_lds[(wc * 64 + n * 16 + r16) * 64 + ((kh * 4 + cc) ^ sw) * 8];
            #pragma unroll
            for (int m = 0; m < 4; ++m)
                #pragma unroll
                for (int n = 0; n < 4; ++n)
                    acc[m][n] = mfma_bf16(af[m], bfr[n], acc[m][n]);
        }
        __syncthreads();
    }

    #pragma unroll
    for (int m = 0; m < 4; ++m) {
        #pragma unroll
        for (int n = 0; n < 4; ++n) {
            #pragma unroll
            for (int j = 0; j < 4; ++j) {
                int row = bm0 + wr * 64 + m * 16 + cc * 4 + j;
                int col = bn0 + wc * 64 + n * 16 + r16;
                float vv = acc[m][n][j];
                if constexpr (EPI == 0)
                    Cb[(size_t)row * Ndim + col] = f2bf(vv);
                else
                    (Cf + (size_t)kz * MROWS * Ndim)[(size_t)row * Ndim + col] = vv;
            }
        }
    }
}

template<int EPI>
__global__ __launch_bounds__(256, 3) void gemm128(
    const unsigned short* __restrict__ A, const unsigned short* __restrict__ WT,
    float* __restrict__ Cf, unsigned short* __restrict__ Cb,
    int Ndim, int Kdim, int ntiles, int nwg, int kspan)
{
    __shared__ __align__(16) unsigned short SMEM[16384];
    gemm128_body<EPI>(SMEM, A, WT, Cf, Cb, Ndim, Kdim, ntiles, nwg, kspan,
                      blockIdx.x, blockIdx.y);
}

// ---------------- fused FF2 (split-K4) + weight conversion -------------------------
template<int MODE>
__global__ __launch_bounds__(256, 3) void ff2_fused_kernel(
    const unsigned short* __restrict__ A, const unsigned short* __restrict__ WT,
    float* __restrict__ Cf,
    const float* __restrict__ Wq, const float* __restrict__ Wk,
    const float* __restrict__ Wv, const float* __restrict__ Wo,
    const float* __restrict__ W1, const float* __restrict__ W2,
    const float* __restrict__ lmW,
    unsigned short* __restrict__ qkvT, unsigned short* __restrict__ woT,
    unsigned short* __restrict__ w1T, unsigned short* __restrict__ w2Tn,
    unsigned short* __restrict__ lmT)
{
    __shared__ __align__(16) unsigned short SMEM[16384];
    int bid = blockIdx.x;
    if (bid < 512) {
        gemm128_body<4>(SMEM, A, WT, Cf, nullptr, EDIM, FFDIM, 8, 128, 1024,
                        bid & 127, bid >> 7);
    } else if constexpr (MODE == 0) {
        wconv_layer_body(SMEM, bid - 512, threadIdx.x, Wq, Wk, Wv, Wo, W1, W2,
                         qkvT, woT, w1T, w2Tn);
    } else {
        int t = bid - 512;
        conv_tile(SMEM, lmW, lmT, EDIM, VOCAB, (t & 15) * 64, (t >> 4) * 64, threadIdx.x);
    }
}

// ---------------- 3-buffer counted-vmcnt GEMM (FF1): 512 thr, 8 waves, 128x256 -----
template<int EPI>
__global__ __launch_bounds__(512, 2) void gemm_p3(
    const unsigned short* __restrict__ A, const unsigned short* __restrict__ WT,
    const float* __restrict__ bias, float* __restrict__ Cf,
    unsigned short* __restrict__ Cb, int Ndim, int Kdim, int mtiles, int ntiles)
{
    __shared__ __align__(16) unsigned short LDS[3][24576];  // per buf: A 16KB | B 32KB
    const int tid = threadIdx.x;
    const int nwg = mtiles * ntiles, q8 = nwg >> 3;
    const int swz = (int)(blockIdx.x & 7) * q8 + (int)(blockIdx.x >> 3);
    const int bn0 = (swz / mtiles) * 256, bm0 = (swz % mtiles) * 128;   // n-major
    const int lane = tid & 63, w = tid >> 6;
    const int wr = w >> 2, wc = w & 3;
    const int r16 = lane & 15, cc = lane >> 4;
    const int lrow = lane >> 3;
    const int lcol = ((lane & 7) ^ lrow) * 8;
    const int sw = r16 & 7;

    f32x4 acc[4][4];
    #pragma unroll
    for (int m = 0; m < 4; ++m)
        #pragma unroll
        for (int n = 0; n < 4; ++n) acc[m][n] = {0.f, 0.f, 0.f, 0.f};

    const int nk = Kdim >> 6;

    auto STAGE = [&](int t, int bufidx) {
        int k0 = t * 64;
        unsigned short* buf = &LDS[bufidx][0];
        #pragma unroll
        for (int i = 0; i < 2; ++i) {
            int c = i * 8 + w;
            gload16(A + (size_t)(bm0 + c * 8 + lrow) * Kdim + k0 + lcol, buf + c * 512);
        }
        #pragma unroll
        for (int i = 0; i < 4; ++i) {
            int c = i * 8 + w;
            gload16(WT + (size_t)(bn0 + c * 8 + lrow) * Kdim + k0 + lcol, buf + 8192 + c * 512);
        }
    };

    STAGE(0, 0);
    STAGE(1, 1);
    asm volatile("s_waitcnt vmcnt(6)" ::: "memory");
    __builtin_amdgcn_sched_barrier(0);
    __builtin_amdgcn_s_barrier();
    __builtin_amdgcn_sched_barrier(0);

    int cur = 0;
    for (int t = 0; t < nk; ++t) {
        if (t + 2 < nk) STAGE(t + 2, cur == 0 ? 2 : cur - 1);
        const unsigned short* Abuf = &LDS[cur][0];
        const unsigned short* Bbuf = &LDS[cur][8192];
        #pragma unroll
        for (int kh = 0; kh < 2; ++kh) {
            short8 af[4], bfr[4];
            #pragma unroll
            for (int m = 0; m < 4; ++m)
                af[m] = *(const short8*)&Abuf[(wr * 64 + m * 16 + r16) * 64 + ((kh * 4 + cc) ^ sw) * 8];
            #pragma unroll
            for (int n = 0; n < 4; ++n)
                bfr[n] = *(const short8*)&Bbuf[(wc * 64 + n * 16 + r16) * 64 + ((kh * 4 + cc) ^ sw) * 8];
            __builtin_amdgcn_s_setprio(1);
            #pragma unroll
            for (int m = 0; m < 4; ++m)
                #pragma unroll
                for (int n = 0; n < 4; ++n)
                    acc[m][n] = mfma_bf16(af[m], bfr[n], acc[m][n]);
            __builtin_amdgcn_s_setprio(0);
        }
        if (t + 1 < nk) {
            if (t + 2 < nk) asm volatile("s_waitcnt vmcnt(6)" ::: "memory");
            else            asm volatile("s_waitcnt vmcnt(0)" ::: "memory");
            __builtin_amdgcn_sched_barrier(0);
            __builtin_amdgcn_s_barrier();
            __builtin_amdgcn_sched_barrier(0);
            asm volatile("" ::: "memory");
        }
        cur = cur == 2 ? 0 : cur + 1;
    }

    #pragma unroll
    for (int m = 0; m < 4; ++m) {
        #pragma unroll
        for (int n = 0; n < 4; ++n) {
            #pragma unroll
            for (int j = 0; j < 4; ++j) {
                int row = bm0 + wr * 64 + m * 16 + cc * 4 + j;
                int col = bn0 + wc * 64 + n * 16 + r16;
                float vv = acc[m][n][j] + bias[col];
                if constexpr (EPI == 2) {
                    vv = 0.5f * vv * (1.0f + erff(vv * 0.70710678118654752f));
                    Cb[(size_t)row * Ndim + col] = f2bf(vv);
                } else {
                    Cf[(size_t)row * Ndim + col] = vv;
                }
            }
        }
    }
}

// ---------------- lm-head GEMM: 256x256, 8 waves (2Mx4N), BK=32, 3-buffer pipeline -
// Per-wave output 128x64 (8m x 4n frags). Staging pre-permutes the GLOBAL source so
// every MFMA fragment read is ds_read_b128 at wave-uniform base + lane*16
// (conflict-free, zero read addr math). Counted vmcnt(4) keeps tile t+2's loads in
// flight across the barrier; tile t+2 targets buffer (t-1)%3, free by construction.
__global__ __launch_bounds__(512, 1) void gemm_8p(
    const unsigned short* __restrict__ A, const unsigned short* __restrict__ WT,
    const float* __restrict__ bias, float* __restrict__ Cf,
    int Ndim, int Kdim, int mtiles, int ntiles)
{
    __shared__ __align__(16) unsigned short LDS[3][16384];  // per buf: A 16KB | B 16KB
    const int tid = threadIdx.x;
    const int nwg = mtiles * ntiles, q8 = nwg >> 3;
    const int swz = (int)(blockIdx.x & 7) * q8 + (int)(blockIdx.x >> 3);
    const int bn0 = (swz / mtiles) * 256, bm0 = (swz % mtiles) * 256;   // n-major
    const int lane = tid & 63, w = tid >> 6;
    const int wr = w >> 2, wc = w & 3;          // 2M x 4N waves
    const int r16 = lane & 15, cc = lane >> 4;  // frag row-in-16 / k-slot; also staging perm

    f32x4 acc[8][4];
    #pragma unroll
    for (int m = 0; m < 8; ++m)
        #pragma unroll
        for (int n = 0; n < 4; ++n) acc[m][n] = {0.f, 0.f, 0.f, 0.f};

    const int nk = Kdim >> 5;   // BK=32, nk >= 2 required (lm: 32)

    // chunk c (0..15) holds rows c*16..c*16+15 x k0..k0+31; cell(lane) =
    // [row c*16+(lane&15)][k (lane>>4)*8..+8] at chunkbase + lane*16
    // prologue: tiles 0,1 (4 loads each, interleaved per tile)
    #pragma unroll
    for (int tt = 0; tt < 2; ++tt) {
        int k0 = tt * 32;
        unsigned short* buf = &LDS[tt][0];
        #pragma unroll
        for (int i = 0; i < 2; ++i) {
            int c = w * 2 + i;
            gload16(A  + (size_t)(bm0 + c * 16 + r16) * Kdim + k0 + cc * 8, buf + c * 512);
            gload16(WT + (size_t)(bn0 + c * 16 + r16) * Kdim + k0 + cc * 8, buf + 8192 + c * 512);
        }
    }
    asm volatile("s_waitcnt vmcnt(4)" ::: "memory");   // tile 0 landed; tile 1 in flight
    __builtin_amdgcn_sched_barrier(0);
    __builtin_amdgcn_s_barrier();
    __builtin_amdgcn_sched_barrier(0);

    int cur = 0;
    for (int t = 0; t < nk; ++t) {
        const unsigned short* Abuf = &LDS[cur][0];
        const unsigned short* Bbuf = &LDS[cur][8192];
        int nxt = cur + 2; if (nxt >= 3) nxt -= 3;    // (t+2)%3 == (t-1)%3: free buffer
        int k2 = (t + 2) * 32;
        // phase A: all B frags + A frags m=0..3; stage t+2's A half
        short8 bf[4], af0[4];
        #pragma unroll
        for (int n = 0; n < 4; ++n)
            bf[n] = *(const short8*)(Bbuf + (wc * 4 + n) * 512 + lane * 8);
        #pragma unroll
        for (int m = 0; m < 4; ++m)
            af0[m] = *(const short8*)(Abuf + (wr * 8 + m) * 512 + lane * 8);
        if (t + 2 < nk) {
            unsigned short* buf = &LDS[nxt][0];
            #pragma unroll
            for (int i = 0; i < 2; ++i) {
                int c = w * 2 + i;
                gload16(A + (size_t)(bm0 + c * 16 + r16) * Kdim + k2 + cc * 8, buf + c * 512);
            }
        }
        __builtin_amdgcn_s_setprio(1);
        #pragma unroll
        for (int m = 0; m < 4; ++m)
            #pragma unroll
            for (int n = 0; n < 4; ++n)
                acc[m][n] = mfma_bf16(af0[m], bf[n], acc[m][n]);
        __builtin_amdgcn_s_setprio(0);
        // phase B: A frags m=4..7; stage t+2's B half
        short8 af1[4];
        #pragma unroll
        for (int m = 0; m < 4; ++m)
            af1[m] = *(const short8*)(Abuf + (wr * 8 + 4 + m) * 512 + lane * 8);
        if (t + 2 < nk) {
            unsigned short* buf = &LDS[nxt][8192];
            #pragma unroll
            for (int i = 0; i < 2; ++i) {
                int c = w * 2 + i;
                gload16(WT + (size_t)(bn0 + c * 16 + r16) * Kdim + k2 + cc * 8, buf + c * 512);
            }
        }
        __builtin_amdgcn_s_setprio(1);
        #pragma unroll
        for (int m = 0; m < 4; ++m)
            #pragma unroll
            for (int n = 0; n < 4; ++n)
                acc[4 + m][n] = mfma_bf16(af1[m], bf[n], acc[4 + m][n]);
        __builtin_amdgcn_s_setprio(0);
        // tile boundary: t+1 landed, t+2 (4 newest loads) stays in flight
        if (t + 1 < nk) {
            if (t + 2 < nk) asm volatile("s_waitcnt vmcnt(4)" ::: "memory");
            else            asm volatile("s_waitcnt vmcnt(0)" ::: "memory");
            __builtin_amdgcn_sched_barrier(0);
            __builtin_amdgcn_s_barrier();
            __builtin_amdgcn_sched_barrier(0);
        }
        cur = cur + 1; if (cur >= 3) cur -= 3;
    }

    #pragma unroll
    for (int m = 0; m < 8; ++m) {
        #pragma unroll
        for (int n = 0; n < 4; ++n) {
            #pragma unroll
            for (int j = 0; j < 4; ++j) {
                int row = bm0 + wr * 128 + m * 16 + cc * 4 + j;
                int col = bn0 + wc * 64 + n * 16 + r16;
                Cf[(size_t)row * Ndim + col] = acc[m][n][j] + bias[col];
            }
        }
    }
}

// ---------------- flash attention: KVBLK=128, exp2 softmax, defer-max, qt-reversed -
__global__ __launch_bounds__(256) void attn_kernel(
    const unsigned short* __restrict__ qkv, unsigned short* __restrict__ o)
{
    __shared__ __align__(16) unsigned short K_lds[128][72];
    __shared__ __align__(16) unsigned short VT_lds[64][136];
    __shared__ __align__(16) unsigned short P_lds[4][16][136];

    int qt = (int)gridDim.x - 1 - (int)blockIdx.x;   // longest blocks first
    int head = blockIdx.y, bb = blockIdx.z;
    int tid = threadIdx.x, w = tid >> 6, lane = tid & 63;
    int r16 = lane & 15, cc = lane >> 4;
    size_t base = ((size_t)bb * TSEQ) * QKVN + head * HDIM;
    const unsigned short* q = qkv + base;
    const unsigned short* k = qkv + base + EDIM;
    const unsigned short* v = qkv + base + 2 * EDIM;
    size_t obase = ((size_t)bb * TSEQ) * EDIM + head * HDIM;
    int qbase = qt * 64;

    const unsigned short* qp = q + (size_t)(qbase + w * 16 + r16) * QKVN;
    short8 aq0 = *(const short8*)(qp + cc * 8);
    short8 aq1 = *(const short8*)(qp + 32 + cc * 8);

    f32x4 oacc[4];
    float m2[4], lrow[4];
    #pragma unroll
    for (int n = 0; n < 4; ++n) oacc[n] = {0.f, 0.f, 0.f, 0.f};
    #pragma unroll
    for (int j = 0; j < 4; ++j) { m2[j] = -1e30f; lrow[j] = 0.f; }

    int krow = tid >> 1, kch = (tid & 1) * 32;
    int vk2 = (tid & 63) * 2, vdb = (tid >> 6) * 16;

    int nkt = (qt + 2) >> 1;
    for (int kt = 0; kt < nkt; ++kt) {
        int kbase = kt * 128;
        const unsigned short* kp = k + (size_t)(kbase + krow) * QKVN + kch;
        *(short8*)&K_lds[krow][kch]      = *(const short8*)kp;
        *(short8*)&K_lds[krow][kch + 8]  = *(const short8*)(kp + 8);
        *(short8*)&K_lds[krow][kch + 16] = *(const short8*)(kp + 16);
        *(short8*)&K_lds[krow][kch + 24] = *(const short8*)(kp + 24);
        const unsigned short* vp0 = v + (size_t)(kbase + vk2) * QKVN + vdb;
        short8 v0a = *(const short8*)vp0;
        short8 v0b = *(const short8*)(vp0 + 8);
        short8 v1a = *(const short8*)(vp0 + QKVN);
        short8 v1b = *(const short8*)(vp0 + QKVN + 8);
        #pragma unroll
        for (int i = 0; i < 8; ++i) {
            *(unsigned*)&VT_lds[vdb + i][vk2] =
                (unsigned)(unsigned short)v0a[i] | ((unsigned)(unsigned short)v1a[i] << 16);
            *(unsigned*)&VT_lds[vdb + 8 + i][vk2] =
                (unsigned)(unsigned short)v0b[i] | ((unsigned)(unsigned short)v1b[i] << 16);
        }
        __syncthreads();

        f32x4 s[8];
        __builtin_amdgcn_s_setprio(1);
        #pragma unroll
        for (int n = 0; n < 8; ++n) {
            short8 bk0 = *(const short8*)&K_lds[n * 16 + r16][cc * 8];
            short8 bk1 = *(const short8*)&K_lds[n * 16 + r16][32 + cc * 8];
            f32x4 z = {0.f, 0.f, 0.f, 0.f};
            z = mfma_bf16(aq0, bk0, z);
            z = mfma_bf16(aq1, bk1, z);
            s[n] = z;
        }
        __builtin_amdgcn_s_setprio(0);
        int myrow = qbase + w * 16 + cc * 4;
        #pragma unroll
        for (int n = 0; n < 8; ++n) {
            int key = kbase + n * 16 + r16;
            #pragma unroll
            for (int j = 0; j < 4; ++j) {
                float sv = s[n][j] * SC2;
                if (key > myrow + j) sv = -1e30f;
                s[n][j] = sv;
            }
        }
        float tmax[4];
        #pragma unroll
        for (int j = 0; j < 4; ++j) {
            float t0 = fmaxf(fmaxf(s[0][j], s[1][j]), fmaxf(s[2][j], s[3][j]));
            float t1 = fmaxf(fmaxf(s[4][j], s[5][j]), fmaxf(s[6][j], s[7][j]));
            float tm = fmaxf(t0, t1);
            #pragma unroll
            for (int mm = 1; mm <= 8; mm <<= 1) tm = fmaxf(tm, __shfl_xor(tm, mm));
            tmax[j] = tm;
        }
        bool defer = (tmax[0] - m2[0] <= 11.5f) && (tmax[1] - m2[1] <= 11.5f)
                  && (tmax[2] - m2[2] <= 11.5f) && (tmax[3] - m2[3] <= 11.5f);
        if (!__all(defer)) {
            #pragma unroll
            for (int j = 0; j < 4; ++j) {
                float mnew = fmaxf(m2[j], tmax[j]);
                float al = exp2f(m2[j] - mnew);
                m2[j] = mnew;
                lrow[j] *= al;
                #pragma unroll
                for (int n = 0; n < 4; ++n) oacc[n][j] *= al;
            }
        }
        #pragma unroll
        for (int j = 0; j < 4; ++j) {
            float ts = 0.f;
            #pragma unroll
            for (int n = 0; n < 8; ++n) {
                float pe = exp2f(s[n][j] - m2[j]);
                s[n][j] = pe;
                ts += pe;
            }
            #pragma unroll
            for (int mm = 1; mm <= 8; mm <<= 1) ts += __shfl_xor(ts, mm);
            lrow[j] += ts;
        }
        #pragma unroll
        for (int n = 0; n < 8; ++n)
            #pragma unroll
            for (int j = 0; j < 4; ++j)
                P_lds[w][cc * 4 + j][n * 16 + r16] = f2bf(s[n][j]);
        short8 pa[4];
        #pragma unroll
        for (int qq = 0; qq < 4; ++qq)
            pa[qq] = *(const short8*)&P_lds[w][r16][qq * 32 + cc * 8];
        __builtin_amdgcn_s_setprio(1);
        #pragma unroll
        for (int n = 0; n < 4; ++n) {
            #pragma unroll
            for (int qq = 0; qq < 4; ++qq) {
                short8 bv = *(const short8*)&VT_lds[n * 16 + r16][qq * 32 + cc * 8];
                oacc[n] = mfma_bf16(pa[qq], bv, oacc[n]);
            }
        }
        __builtin_amdgcn_s_setprio(0);
        __syncthreads();
    }
    float rl[4];
    #pragma unroll
    for (int j = 0; j < 4; ++j) rl[j] = 1.0f / lrow[j];
    #pragma unroll
    for (int n = 0; n < 4; ++n)
        #pragma unroll
        for (int j = 0; j < 4; ++j) {
            int row = qbase + w * 16 + cc * 4 + j;
            o[obase + (size_t)row * EDIM + n * 16 + r16] = f2bf(oacc[n][j] * rl[j]);
        }
}

extern "C" void kernel_launch(void* const* d_in, const int* in_sizes, int n_in,
                              void* d_out, int out_size, void* d_ws, size_t ws_size,
                              hipStream_t stream) {
    const int*   idx     = (const int*)d_in[0];
    const float* tok_emb = (const float*)d_in[1];
    const float* pos_emb = (const float*)d_in[2];
    const float* Wq      = (const float*)d_in[3];
    const float* Wk      = (const float*)d_in[4];
    const float* Wv      = (const float*)d_in[5];
    const float* Wo      = (const float*)d_in[6];
    const float* bo      = (const float*)d_in[7];
    const float* ln1_s   = (const float*)d_in[8];
    const float* ln1_b   = (const float*)d_in[9];
    const float* W1      = (const float*)d_in[10];
    const float* b1      = (const float*)d_in[11];
    const float* W2      = (const float*)d_in[12];
    const float* b2      = (const float*)d_in[13];
    const float* ln2_s   = (const float*)d_in[14];
    const float* ln2_b   = (const float*)d_in[15];
    const float* lnf_s   = (const float*)d_in[16];
    const float* lnf_b   = (const float*)d_in[17];
    const float* lm_w    = (const float*)d_in[18];
    const float* lm_b    = (const float*)d_in[19];
    float* out = (float*)d_out;

    const size_t MB = 1 << 20;
    char* ws = (char*)d_ws;
    float*          x    = (float*)ws;                                  // 0..8 MB
    unsigned short* h    = (unsigned short*)(ws + 8 * MB);              // 8..12
    unsigned short* qkv  = (unsigned short*)(ws + 12 * MB);             // 12..24
    unsigned short* ao   = (unsigned short*)(ws + 24 * MB);             // 24..28
    unsigned short* ff   = (unsigned short*)(ws + 28 * MB);             // 28..44
    unsigned short* qkvT = (unsigned short*)(ws + 44 * MB);             // 44..50
    unsigned short* woT  = (unsigned short*)(ws + 50 * MB);             // 50..52
    unsigned short* w1T  = (unsigned short*)(ws + 52 * MB);             // 52..60
    unsigned short* w2Ta = (unsigned short*)(ws + 60 * MB);             // 60..68
    unsigned short* lmT  = (unsigned short*)(ws + 68 * MB);             // 68..130.5

    bool tier1 = ws_size >= (size_t)140 * MB;
    bool tier2 = ws_size >= (size_t)172 * MB;
    unsigned short* w2Tb = tier1 ? (unsigned short*)(ws + 131 * MB) : w2Ta;
    float* part = (float*)(ws + (tier2 ? (size_t)139 * MB : (size_t)68 * MB));

    dim3 blk(256);
    embed_ln_kernel<<<MROWS, blk, 0, stream>>>(idx, tok_emb, pos_emb, x, ln1_s, ln1_b, h);
    wconv_layer_kernel<<<3072, blk, 0, stream>>>(Wq, Wk, Wv, Wo, W1, W2,
                                                 qkvT, woT, w1T, w2Ta);

    for (int l = 0; l < NLAYERS; ++l) {
        unsigned short* w2cur = (l & 1) ? w2Tb : w2Ta;
        unsigned short* w2nxt = ((l + 1) & 1) ? w2Tb : w2Ta;
        size_t eo1 = (size_t)(l + 1) * EDIM * EDIM;

        // QKV: M2048 N3072 K1024 -> 16x24 = 384 wg
        gemm128<0><<<dim3(384, 1), blk, 0, stream>>>(h, qkvT, nullptr, qkv, QKVN, EDIM, 24, 384, EDIM);
        attn_kernel<<<dim3(TSEQ / 64, NHEADS, NBATCH), blk, 0, stream>>>(qkv, ao);
        // Wo: N1024 K1024, 16x8 = 128 wg x kz4 (kspan 256)
        gemm128<4><<<dim3(128, 4), blk, 0, stream>>>(ao, woT, part, nullptr, EDIM, EDIM, 8, 128, 256);
        reduce_ln_kernel<4><<<MROWS, blk, 0, stream>>>(part, bo + l * EDIM, x, ln2_s + l * EDIM, ln2_b + l * EDIM, h);
        // FF1: M2048 N4096 K1024 -> 3-buffer pipeline, 256 wg of 512 thr
        gemm_p3<2><<<dim3(256, 1), dim3(512), 0, stream>>>(h, w1T, b1 + l * FFDIM, nullptr, ff, FFDIM, EDIM, 16, 16);
        // FF2 (+ overlapped weight conversion for next layer / lm head)
        if (l < NLAYERS - 1) {
            if (tier1)
                ff2_fused_kernel<0><<<3584, blk, 0, stream>>>(
                    ff, w2cur, part,
                    Wq + eo1, Wk + eo1, Wv + eo1, Wo + eo1,
                    W1 + (size_t)(l + 1) * EDIM * FFDIM, W2 + (size_t)(l + 1) * FFDIM * EDIM,
                    nullptr, qkvT, woT, w1T, w2nxt, nullptr);
            else {
                gemm128<4><<<dim3(128, 4), blk, 0, stream>>>(ff, w2cur, part, nullptr, EDIM, FFDIM, 8, 128, 1024);
                wconv_layer_kernel<<<3072, blk, 0, stream>>>(
                    Wq + eo1, Wk + eo1, Wv + eo1, Wo + eo1,
                    W1 + (size_t)(l + 1) * EDIM * FFDIM, W2 + (size_t)(l + 1) * FFDIM * EDIM,
                    qkvT, woT, w1T, w2nxt);
            }
        } else {
            if (tier2)
                ff2_fused_kernel<1><<<8512, blk, 0, stream>>>(
                    ff, w2cur, part,
                    nullptr, nullptr, nullptr, nullptr, nullptr, nullptr,
                    lm_w, nullptr, nullptr, nullptr, nullptr, lmT);
            else
                gemm128<4><<<dim3(128, 4), blk, 0, stream>>>(ff, w2cur, part, nullptr, EDIM, FFDIM, 8, 128, 1024);
        }
        if (l < NLAYERS - 1)
            reduce_ln_kernel<4><<<MROWS, blk, 0, stream>>>(part, b2 + l * EDIM, x, ln1_s + (l + 1) * EDIM, ln1_b + (l + 1) * EDIM, h);
        else
            reduce_ln_kernel<4><<<MROWS, blk, 0, stream>>>(part, b2 + l * EDIM, x, lnf_s, lnf_b, h);
    }
    if (!tier2)
        wconv_kernel<<<dim3(16, 500), blk, 0, stream>>>(lm_w, lmT, EDIM, VOCAB);
    // lm head: M2048 N32000 K1024 -> 8m x 125n (n-major) = 1000 wg of 512 thr
    gemm_8p<<<dim3(1000, 1), dim3(512), 0, stream>>>(h, lmT, lm_b, out, VOCAB, EDIM, 8, 125);
}

// Round 10
// 1427.349 us; speedup vs baseline: 1.0226x; 1.0226x over previous
//
#include <hip/hip_runtime.h>

#define EDIM 1024
#define NHEADS 16
#define HDIM 64
#define TSEQ 1024
#define NBATCH 2
#define MROWS 2048
#define FFDIM 4096
#define NLAYERS 8
#define VOCAB 32000
#define QKVN 3072
#define SC2 0.18033688011112042f   /* 0.125 * log2(e) */

typedef __attribute__((ext_vector_type(4))) float f32x4;
typedef __attribute__((ext_vector_type(8))) short short8;

__device__ __forceinline__ unsigned short f2bf(float f) {
    union { float f; unsigned u; } v; v.f = f;
    unsigned r = v.u + 0x7fffu + ((v.u >> 16) & 1u);
    return (unsigned short)(r >> 16);
}

__device__ __forceinline__ float bf2f(unsigned u) {
    union { unsigned u; float f; } v; v.u = u << 16; return v.f;
}

__device__ __forceinline__ f32x4 mfma_bf16(short8 a, short8 b, f32x4 c) {
    return __builtin_amdgcn_mfma_f32_16x16x32_bf16(a, b, c, 0, 0, 0);
}

// async global->LDS, 16B per lane; LDS dest = wave-uniform base + lane*16
__device__ __forceinline__ void gload16(const unsigned short* g, unsigned short* l) {
    __builtin_amdgcn_global_load_lds(
        (const __attribute__((address_space(1))) unsigned int*)g,
        (__attribute__((address_space(3))) unsigned int*)l, 16, 0, 0);
}

// ---------------- LN core ----------------
__device__ __forceinline__ void ln_store(
    f32x4 v, int tid, const float* __restrict__ sc, const float* __restrict__ bi,
    unsigned short* __restrict__ hrow)
{
    float sum = v[0] + v[1] + v[2] + v[3];
    float sq = v[0]*v[0] + v[1]*v[1] + v[2]*v[2] + v[3]*v[3];
    #pragma unroll
    for (int m = 1; m <= 32; m <<= 1) { sum += __shfl_xor(sum, m); sq += __shfl_xor(sq, m); }
    __shared__ float sh[8];
    int w = tid >> 6;
    if ((tid & 63) == 0) { sh[w] = sum; sh[4 + w] = sq; }
    __syncthreads();
    sum = sh[0] + sh[1] + sh[2] + sh[3];
    sq  = sh[4] + sh[5] + sh[6] + sh[7];
    float mu = sum * (1.0f / EDIM);
    float inv = rsqrtf(sq * (1.0f / EDIM) - mu * mu + 1e-5f);
    int c = tid * 4;
    unsigned o0 = (unsigned)f2bf((v[0] - mu) * inv * sc[c + 0] + bi[c + 0])
                | ((unsigned)f2bf((v[1] - mu) * inv * sc[c + 1] + bi[c + 1]) << 16);
    unsigned o1 = (unsigned)f2bf((v[2] - mu) * inv * sc[c + 2] + bi[c + 2])
                | ((unsigned)f2bf((v[3] - mu) * inv * sc[c + 3] + bi[c + 3]) << 16);
    unsigned* hp = (unsigned*)(hrow + c);
    hp[0] = o0; hp[1] = o1;
}

// ---------------- embedding + first LN fused ----------------
__global__ __launch_bounds__(256) void embed_ln_kernel(
    const int* __restrict__ idx, const float* __restrict__ tok,
    const float* __restrict__ pos, float* __restrict__ x,
    const float* __restrict__ sc, const float* __restrict__ bi,
    unsigned short* __restrict__ h)
{
    int row = blockIdx.x, tid = threadIdx.x;
    int t = row & (TSEQ - 1);
    int tokid = idx[row];
    int c = tid * 4;
    f32x4 a = *(const f32x4*)(tok + (size_t)tokid * EDIM + c);
    f32x4 b = *(const f32x4*)(pos + (size_t)t * EDIM + c);
    f32x4 v = a + b;
    *(f32x4*)(x + (size_t)row * EDIM + c) = v;
    ln_store(v, tid, sc, bi, h + (size_t)row * EDIM);
}

// fused: x += bias + sum_kz part(bf16);  h = LN(x)
template<int KZ>
__global__ __launch_bounds__(256) void reduce_ln_kernel(
    const unsigned short* __restrict__ part, const float* __restrict__ bias,
    float* __restrict__ x, const float* __restrict__ sc,
    const float* __restrict__ bi, unsigned short* __restrict__ h)
{
    int row = blockIdx.x, tid = threadIdx.x;
    int c = tid * 4;
    f32x4 s = *(const f32x4*)(x + (size_t)row * EDIM + c);
    s += *(const f32x4*)(bias + c);
    #pragma unroll
    for (int kz = 0; kz < KZ; ++kz) {
        const unsigned* p = (const unsigned*)(part + ((size_t)kz * MROWS + row) * EDIM + c);
        unsigned p0 = p[0], p1 = p[1];
        s[0] += bf2f(p0); s[1] += bf2f(p0 >> 16);
        s[2] += bf2f(p1); s[3] += bf2f(p1 >> 16);
    }
    *(f32x4*)(x + (size_t)row * EDIM + c) = s;
    ln_store(s, tid, sc, bi, h + (size_t)row * EDIM);
}

// ---------------- weight convert+transpose tile (64x64), LDS passed in ----------
__device__ __forceinline__ void conv_tile(
    unsigned short* __restrict__ Tb,   // >= 64*72 shorts
    const float* __restrict__ W, unsigned short* __restrict__ WT,
    int Kdim, int Ndim, int k0, int n0, int tid)
{
    int r = tid >> 4, c4 = (tid & 15) * 4;
    #pragma unroll
    for (int i = 0; i < 4; ++i) {
        f32x4 v = *(const f32x4*)(W + (size_t)(k0 + r + 16 * i) * Ndim + n0 + c4);
        Tb[(c4 + 0) * 72 + r + 16 * i] = f2bf(v[0]);
        Tb[(c4 + 1) * 72 + r + 16 * i] = f2bf(v[1]);
        Tb[(c4 + 2) * 72 + r + 16 * i] = f2bf(v[2]);
        Tb[(c4 + 3) * 72 + r + 16 * i] = f2bf(v[3]);
    }
    __syncthreads();
    int nr = tid >> 2, kc = (tid & 3) * 16;
    short8 o0 = *(const short8*)&Tb[nr * 72 + kc];
    short8 o1 = *(const short8*)&Tb[nr * 72 + kc + 8];
    *(short8*)(WT + (size_t)(n0 + nr) * Kdim + k0 + kc)     = o0;
    *(short8*)(WT + (size_t)(n0 + nr) * Kdim + k0 + kc + 8) = o1;
}

// conv dispatcher over one layer's 6 weights; t in [0, 3072)
__device__ __forceinline__ void wconv_layer_body(
    unsigned short* Tb, int t, int tid,
    const float* Wq, const float* Wk, const float* Wv, const float* Wo,
    const float* W1, const float* W2,
    unsigned short* qkvT, unsigned short* woT,
    unsigned short* w1T, unsigned short* w2T)
{
    if (t < 768) {
        int wsel = t >> 8, tt = t & 255;
        const float* src = wsel == 0 ? Wq : (wsel == 1 ? Wk : Wv);
        conv_tile(Tb, src, qkvT + (size_t)wsel * EDIM * EDIM, EDIM, EDIM,
                  (tt & 15) * 64, (tt >> 4) * 64, tid);
    } else if (t < 1024) {
        int tt = t - 768;
        conv_tile(Tb, Wo, woT, EDIM, EDIM, (tt & 15) * 64, (tt >> 4) * 64, tid);
    } else if (t < 2048) {
        int tt = t - 1024;
        conv_tile(Tb, W1, w1T, EDIM, FFDIM, (tt & 15) * 64, (tt >> 4) * 64, tid);
    } else {
        int tt = t - 2048;
        conv_tile(Tb, W2, w2T, FFDIM, EDIM, (tt >> 4) * 64, (tt & 15) * 64, tid);
    }
}

__global__ __launch_bounds__(256) void wconv_layer_kernel(
    const float* __restrict__ Wq, const float* __restrict__ Wk,
    const float* __restrict__ Wv, const float* __restrict__ Wo,
    const float* __restrict__ W1, const float* __restrict__ W2,
    unsigned short* __restrict__ qkvT, unsigned short* __restrict__ woT,
    unsigned short* __restrict__ w1T, unsigned short* __restrict__ w2T)
{
    __shared__ __align__(16) unsigned short Tb[64 * 72];
    wconv_layer_body(Tb, blockIdx.x, threadIdx.x, Wq, Wk, Wv, Wo, W1, W2,
                     qkvT, woT, w1T, w2T);
}

__global__ __launch_bounds__(256) void wconv_kernel(
    const float* __restrict__ W, unsigned short* __restrict__ WT, int Kdim, int Ndim)
{
    __shared__ __align__(16) unsigned short Tb[64 * 72];
    conv_tile(Tb, W, WT, Kdim, Ndim, blockIdx.x * 64, blockIdx.y * 64, threadIdx.x);
}

// ---------------- narrow GEMM body: block 128x128, 4 waves, BK=64, XOR-swizzle ----
// EPI 0: ->bf16   4: partial bf16 (split-K, Cb indexed by kz)
template<int EPI>
__device__ __forceinline__ void gemm128_body(
    unsigned short* SMEM,   // >= 16384 shorts (A 8192 | B 8192)
    const unsigned short* __restrict__ A, const unsigned short* __restrict__ WT,
    unsigned short* __restrict__ Cb,
    int Ndim, int Kdim, int ntiles, int nwg, int kspan, int bid, int kz)
{
    unsigned short* A_lds = SMEM;
    unsigned short* B_lds = SMEM + 8192;
    int tid = threadIdx.x;
    int q8 = nwg >> 3;
    int swz = (bid & 7) * q8 + (bid >> 3);
    int bm0 = (swz / ntiles) * 128, bn0 = (swz % ntiles) * 128;
    int lane = tid & 63, w = tid >> 6;
    int wr = w >> 1, wc = w & 1;
    int r16 = lane & 15, cc = lane >> 4;
    int lrow = lane >> 3;
    int lcol = ((lane & 7) ^ lrow) * 8;
    int sw = r16 & 7;

    f32x4 acc[4][4];
    #pragma unroll
    for (int m = 0; m < 4; ++m)
        #pragma unroll
        for (int n = 0; n < 4; ++n) acc[m][n] = {0.f, 0.f, 0.f, 0.f};

    int kbeg = kz * kspan, kend = kbeg + kspan;
    for (int k0 = kbeg; k0 < kend; k0 += 64) {
        #pragma unroll
        for (int i = 0; i < 4; ++i) {
            int c = i * 4 + w;
            gload16(A + (size_t)(bm0 + c * 8 + lrow) * Kdim + k0 + lcol, A_lds + c * 512);
            gload16(WT + (size_t)(bn0 + c * 8 + lrow) * Kdim + k0 + lcol, B_lds + c * 512);
        }
        __syncthreads();
        #pragma unroll
        for (int kh = 0; kh < 2; ++kh) {
            short8 af[4], bfr[4];
            #pragma unroll
            for (int m = 0; m < 4; ++m)
                af[m] = *(const short8*)&A_lds[(wr * 64 + m * 16 + r16) * 64 + ((kh * 4 + cc) ^ sw) * 8];
            #pragma unroll
            for (int n = 0; n < 4; ++n)
                bfr[n] = *(const short8*)&B_lds[(wc * 64 + n * 16 + r16) * 64 + ((kh * 4 + cc) ^ sw) * 8];
            #pragma unroll
            for (int m = 0; m < 4; ++m)
                #pragma unroll
                for (int n = 0; n < 4; ++n)
                    acc[m][n] = mfma_bf16(af[m], bfr[n], acc[m][n]);
        }
        __syncthreads();
    }

    #pragma unroll
    for (int m = 0; m < 4; ++m) {
        #pragma unroll
        for (int n = 0; n < 4; ++n) {
            #pragma unroll
            for (int j = 0; j < 4; ++j) {
                int row = bm0 + wr * 64 + m * 16 + cc * 4 + j;
                int col = bn0 + wc * 64 + n * 16 + r16;
                float vv = acc[m][n][j];
                if constexpr (EPI == 0)
                    Cb[(size_t)row * Ndim + col] = f2bf(vv);
                else
                    Cb[((size_t)kz * MROWS + row) * Ndim + col] = f2bf(vv);
            }
        }
    }
}

template<int EPI>
__global__ __launch_bounds__(256, 3) void gemm128(
    const unsigned short* __restrict__ A, const unsigned short* __restrict__ WT,
    unsigned short* __restrict__ Cb,
    int Ndim, int Kdim, int ntiles, int nwg, int kspan)
{
    __shared__ __align__(16) unsigned short SMEM[16384];
    gemm128_body<EPI>(SMEM, A, WT, Cb, Ndim, Kdim, ntiles, nwg, kspan,
                      blockIdx.x, blockIdx.y);
}

// ---------------- fused FF2 (split-K4, bf16 partials) + weight conversion ----------
template<int MODE>
__global__ __launch_bounds__(256, 3) void ff2_fused_kernel(
    const unsigned short* __restrict__ A, const unsigned short* __restrict__ WT,
    unsigned short* __restrict__ Cp,
    const float* __restrict__ Wq, const float* __restrict__ Wk,
    const float* __restrict__ Wv, const float* __restrict__ Wo,
    const float* __restrict__ W1, const float* __restrict__ W2,
    const float* __restrict__ lmW,
    unsigned short* __restrict__ qkvT, unsigned short* __restrict__ woT,
    unsigned short* __restrict__ w1T, unsigned short* __restrict__ w2Tn,
    unsigned short* __restrict__ lmT)
{
    __shared__ __align__(16) unsigned short SMEM[16384];
    int bid = blockIdx.x;
    if (bid < 512) {
        gemm128_body<4>(SMEM, A, WT, Cp, EDIM, FFDIM, 8, 128, 1024,
                        bid & 127, bid >> 7);
    } else if constexpr (MODE == 0) {
        wconv_layer_body(SMEM, bid - 512, threadIdx.x, Wq, Wk, Wv, Wo, W1, W2,
                         qkvT, woT, w1T, w2Tn);
    } else {
        int t = bid - 512;
        conv_tile(SMEM, lmW, lmT, EDIM, VOCAB, (t & 15) * 64, (t >> 4) * 64, threadIdx.x);
    }
}

// ---------------- 3-buffer counted-vmcnt GEMM (FF1): 512 thr, 8 waves, 128x256 -----
template<int EPI>
__global__ __launch_bounds__(512, 2) void gemm_p3(
    const unsigned short* __restrict__ A, const unsigned short* __restrict__ WT,
    const float* __restrict__ bias, float* __restrict__ Cf,
    unsigned short* __restrict__ Cb, int Ndim, int Kdim, int mtiles, int ntiles)
{
    __shared__ __align__(16) unsigned short LDS[3][24576];  // per buf: A 16KB | B 32KB
    const int tid = threadIdx.x;
    const int nwg = mtiles * ntiles, q8 = nwg >> 3;
    const int swz = (int)(blockIdx.x & 7) * q8 + (int)(blockIdx.x >> 3);
    const int bn0 = (swz / mtiles) * 256, bm0 = (swz % mtiles) * 128;   // n-major
    const int lane = tid & 63, w = tid >> 6;
    const int wr = w >> 2, wc = w & 3;
    const int r16 = lane & 15, cc = lane >> 4;
    const int lrow = lane >> 3;
    const int lcol = ((lane & 7) ^ lrow) * 8;
    const int sw = r16 & 7;

    f32x4 acc[4][4];
    #pragma unroll
    for (int m = 0; m < 4; ++m)
        #pragma unroll
        for (int n = 0; n < 4; ++n) acc[m][n] = {0.f, 0.f, 0.f, 0.f};

    const int nk = Kdim >> 6;

    auto STAGE = [&](int t, int bufidx) {
        int k0 = t * 64;
        unsigned short* buf = &LDS[bufidx][0];
        #pragma unroll
        for (int i = 0; i < 2; ++i) {
            int c = i * 8 + w;
            gload16(A + (size_t)(bm0 + c * 8 + lrow) * Kdim + k0 + lcol, buf + c * 512);
        }
        #pragma unroll
        for (int i = 0; i < 4; ++i) {
            int c = i * 8 + w;
            gload16(WT + (size_t)(bn0 + c * 8 + lrow) * Kdim + k0 + lcol, buf + 8192 + c * 512);
        }
    };

    STAGE(0, 0);
    STAGE(1, 1);
    asm volatile("s_waitcnt vmcnt(6)" ::: "memory");
    __builtin_amdgcn_sched_barrier(0);
    __builtin_amdgcn_s_barrier();
    __builtin_amdgcn_sched_barrier(0);

    int cur = 0;
    for (int t = 0; t < nk; ++t) {
        if (t + 2 < nk) STAGE(t + 2, cur == 0 ? 2 : cur - 1);
        const unsigned short* Abuf = &LDS[cur][0];
        const unsigned short* Bbuf = &LDS[cur][8192];
        #pragma unroll
        for (int kh = 0; kh < 2; ++kh) {
            short8 af[4], bfr[4];
            #pragma unroll
            for (int m = 0; m < 4; ++m)
                af[m] = *(const short8*)&Abuf[(wr * 64 + m * 16 + r16) * 64 + ((kh * 4 + cc) ^ sw) * 8];
            #pragma unroll
            for (int n = 0; n < 4; ++n)
                bfr[n] = *(const short8*)&Bbuf[(wc * 64 + n * 16 + r16) * 64 + ((kh * 4 + cc) ^ sw) * 8];
            __builtin_amdgcn_s_setprio(1);
            #pragma unroll
            for (int m = 0; m < 4; ++m)
                #pragma unroll
                for (int n = 0; n < 4; ++n)
                    acc[m][n] = mfma_bf16(af[m], bfr[n], acc[m][n]);
            __builtin_amdgcn_s_setprio(0);
        }
        if (t + 1 < nk) {
            if (t + 2 < nk) asm volatile("s_waitcnt vmcnt(6)" ::: "memory");
            else            asm volatile("s_waitcnt vmcnt(0)" ::: "memory");
            __builtin_amdgcn_sched_barrier(0);
            __builtin_amdgcn_s_barrier();
            __builtin_amdgcn_sched_barrier(0);
            asm volatile("" ::: "memory");
        }
        cur = cur == 2 ? 0 : cur + 1;
    }

    #pragma unroll
    for (int m = 0; m < 4; ++m) {
        #pragma unroll
        for (int n = 0; n < 4; ++n) {
            #pragma unroll
            for (int j = 0; j < 4; ++j) {
                int row = bm0 + wr * 64 + m * 16 + cc * 4 + j;
                int col = bn0 + wc * 64 + n * 16 + r16;
                float vv = acc[m][n][j] + bias[col];
                if constexpr (EPI == 2) {
                    vv = 0.5f * vv * (1.0f + erff(vv * 0.70710678118654752f));
                    Cb[(size_t)row * Ndim + col] = f2bf(vv);
                } else {
                    Cf[(size_t)row * Ndim + col] = vv;
                }
            }
        }
    }
}

// ---------------- wide GEMM (lm head): block 128Mx256N, wave 64x128, n-major -------
__global__ __launch_bounds__(256, 2) void gemm_wide_lm(
    const unsigned short* __restrict__ A, const unsigned short* __restrict__ WT,
    const float* __restrict__ bias, float* __restrict__ Cf,
    int Ndim, int Kdim, int mtiles, int ntiles)
{
    __shared__ __align__(16) unsigned short A_lds[128][64];
    __shared__ __align__(16) unsigned short B_lds[256][64];
    int tid = threadIdx.x;
    int nwg = mtiles * ntiles;
    int q8 = nwg >> 3;
    int swz = (int)(blockIdx.x & 7) * q8 + (int)(blockIdx.x >> 3);
    int bn0 = (swz / mtiles) * 256, bm0 = (swz % mtiles) * 128;
    int lane = tid & 63, w = tid >> 6;
    int wr = w >> 1, wc = w & 1;
    int r16 = lane & 15, cc = lane >> 4;
    int lrow = lane >> 3;
    int lcol = ((lane & 7) ^ lrow) * 8;
    int sw = r16 & 7;

    f32x4 acc[4][8];
    #pragma unroll
    for (int m = 0; m < 4; ++m)
        #pragma unroll
        for (int n = 0; n < 8; ++n) acc[m][n] = {0.f, 0.f, 0.f, 0.f};

    for (int k0 = 0; k0 < Kdim; k0 += 64) {
        #pragma unroll
        for (int i = 0; i < 4; ++i) {
            int c = i * 4 + w;
            gload16(A + (size_t)(bm0 + c * 8 + lrow) * Kdim + k0 + lcol,
                    (unsigned short*)A_lds + c * 512);
        }
        #pragma unroll
        for (int i = 0; i < 8; ++i) {
            int c = i * 4 + w;
            gload16(WT + (size_t)(bn0 + c * 8 + lrow) * Kdim + k0 + lcol,
                    (unsigned short*)B_lds + c * 512);
        }
        __syncthreads();
        #pragma unroll
        for (int kh = 0; kh < 2; ++kh) {
            short8 af[4], bfr[8];
            #pragma unroll
            for (int m = 0; m < 4; ++m)
                af[m] = *(const short8*)&A_lds[wr * 64 + m * 16 + r16][((kh * 4 + cc) ^ sw) * 8];
            #pragma unroll
            for (int n = 0; n < 8; ++n)
                bfr[n] = *(const short8*)&B_lds[wc * 128 + n * 16 + r16][((kh * 4 + cc) ^ sw) * 8];
            #pragma unroll
            for (int m = 0; m < 4; ++m)
                #pragma unroll
                for (int n = 0; n < 8; ++n)
                    acc[m][n] = mfma_bf16(af[m], bfr[n], acc[m][n]);
        }
        __syncthreads();
    }

    #pragma unroll
    for (int m = 0; m < 4; ++m) {
        #pragma unroll
        for (int n = 0; n < 8; ++n) {
            #pragma unroll
            for (int j = 0; j < 4; ++j) {
                int row = bm0 + wr * 64 + m * 16 + cc * 4 + j;
                int col = bn0 + wc * 128 + n * 16 + r16;
                Cf[(size_t)row * Ndim + col] = acc[m][n][j] + bias[col];
            }
        }
    }
}

// ---------------- flash attention: KVBLK=128, diag-specialized causal --------------
__global__ __launch_bounds__(256) void attn_kernel(
    const unsigned short* __restrict__ qkv, unsigned short* __restrict__ o)
{
    __shared__ __align__(16) unsigned short K_lds[128][72];
    __shared__ __align__(16) unsigned short VT_lds[64][136];
    __shared__ __align__(16) unsigned short P_lds[4][16][136];

    int qt = (int)gridDim.x - 1 - (int)blockIdx.x;   // longest blocks first
    int head = blockIdx.y, bb = blockIdx.z;
    int tid = threadIdx.x, w = tid >> 6, lane = tid & 63;
    int r16 = lane & 15, cc = lane >> 4;
    size_t base = ((size_t)bb * TSEQ) * QKVN + head * HDIM;
    const unsigned short* q = qkv + base;
    const unsigned short* k = qkv + base + EDIM;
    const unsigned short* v = qkv + base + 2 * EDIM;
    size_t obase = ((size_t)bb * TSEQ) * EDIM + head * HDIM;
    int qbase = qt * 64;

    const unsigned short* qp = q + (size_t)(qbase + w * 16 + r16) * QKVN;
    short8 aq0 = *(const short8*)(qp + cc * 8);
    short8 aq1 = *(const short8*)(qp + 32 + cc * 8);

    f32x4 oacc[4];
    float m2[4], lrow[4];
    #pragma unroll
    for (int n = 0; n < 4; ++n) oacc[n] = {0.f, 0.f, 0.f, 0.f};
    #pragma unroll
    for (int j = 0; j < 4; ++j) { m2[j] = -1e30f; lrow[j] = 0.f; }

    int krow = tid >> 1, kch = (tid & 1) * 32;
    int vk2 = (tid & 63) * 2, vdb = (tid >> 6) * 16;
    int myrow = qbase + w * 16 + cc * 4;

    int nkt = (qt + 2) >> 1;
    for (int kt = 0; kt < nkt; ++kt) {
        int kbase = kt * 128;
        bool last = (kt == nkt - 1);
        bool half = last && !(qt & 1);    // frags 4..7 fully masked -> dead
        if (!half || krow < 64) {
            const unsigned short* kp = k + (size_t)(kbase + krow) * QKVN + kch;
            *(short8*)&K_lds[krow][kch]      = *(const short8*)kp;
            *(short8*)&K_lds[krow][kch + 8]  = *(const short8*)(kp + 8);
            *(short8*)&K_lds[krow][kch + 16] = *(const short8*)(kp + 16);
            *(short8*)&K_lds[krow][kch + 24] = *(const short8*)(kp + 24);
        }
        if (!half || vk2 < 64) {
            const unsigned short* vp0 = v + (size_t)(kbase + vk2) * QKVN + vdb;
            short8 v0a = *(const short8*)vp0;
            short8 v0b = *(const short8*)(vp0 + 8);
            short8 v1a = *(const short8*)(vp0 + QKVN);
            short8 v1b = *(const short8*)(vp0 + QKVN + 8);
            #pragma unroll
            for (int i = 0; i < 8; ++i) {
                *(unsigned*)&VT_lds[vdb + i][vk2] =
                    (unsigned)(unsigned short)v0a[i] | ((unsigned)(unsigned short)v1a[i] << 16);
                *(unsigned*)&VT_lds[vdb + 8 + i][vk2] =
                    (unsigned)(unsigned short)v0b[i] | ((unsigned)(unsigned short)v1b[i] << 16);
            }
        }
        __syncthreads();

        f32x4 s[8];
        __builtin_amdgcn_s_setprio(1);
        #pragma unroll
        for (int n = 0; n < 4; ++n) {
            short8 bk0 = *(const short8*)&K_lds[n * 16 + r16][cc * 8];
            short8 bk1 = *(const short8*)&K_lds[n * 16 + r16][32 + cc * 8];
            f32x4 z = {0.f, 0.f, 0.f, 0.f};
            z = mfma_bf16(aq0, bk0, z);
            z = mfma_bf16(aq1, bk1, z);
            s[n] = z;
        }
        __builtin_amdgcn_s_setprio(0);
        if (!half) {
            __builtin_amdgcn_s_setprio(1);
            #pragma unroll
            for (int n = 4; n < 8; ++n) {
                short8 bk0 = *(const short8*)&K_lds[n * 16 + r16][cc * 8];
                short8 bk1 = *(const short8*)&K_lds[n * 16 + r16][32 + cc * 8];
                f32x4 z = {0.f, 0.f, 0.f, 0.f};
                z = mfma_bf16(aq0, bk0, z);
                z = mfma_bf16(aq1, bk1, z);
                s[n] = z;
            }
            __builtin_amdgcn_s_setprio(0);
        }

        // scale (+ triangular mask only where needed)
        if (last) {
            if (half) {
                #pragma unroll
                for (int n = 0; n < 4; ++n) {
                    int key = kbase + n * 16 + r16;
                    #pragma unroll
                    for (int j = 0; j < 4; ++j) {
                        float sv = s[n][j] * SC2;
                        if (key > myrow + j) sv = -1e30f;
                        s[n][j] = sv;
                    }
                }
            } else {
                #pragma unroll
                for (int n = 0; n < 4; ++n)
                    #pragma unroll
                    for (int j = 0; j < 4; ++j) s[n][j] *= SC2;
                #pragma unroll
                for (int n = 4; n < 8; ++n) {
                    int key = kbase + n * 16 + r16;
                    #pragma unroll
                    for (int j = 0; j < 4; ++j) {
                        float sv = s[n][j] * SC2;
                        if (key > myrow + j) sv = -1e30f;
                        s[n][j] = sv;
                    }
                }
            }
        } else {
            #pragma unroll
            for (int n = 0; n < 8; ++n)
                #pragma unroll
                for (int j = 0; j < 4; ++j) s[n][j] *= SC2;
        }

        float tmax[4];
        #pragma unroll
        for (int j = 0; j < 4; ++j) {
            float tm = fmaxf(fmaxf(s[0][j], s[1][j]), fmaxf(s[2][j], s[3][j]));
            if (!half) tm = fmaxf(tm, fmaxf(fmaxf(s[4][j], s[5][j]), fmaxf(s[6][j], s[7][j])));
            #pragma unroll
            for (int mm = 1; mm <= 8; mm <<= 1) tm = fmaxf(tm, __shfl_xor(tm, mm));
            tmax[j] = tm;
        }
        bool defer = (tmax[0] - m2[0] <= 11.5f) && (tmax[1] - m2[1] <= 11.5f)
                  && (tmax[2] - m2[2] <= 11.5f) && (tmax[3] - m2[3] <= 11.5f);
        if (!__all(defer)) {
            #pragma unroll
            for (int j = 0; j < 4; ++j) {
                float mnew = fmaxf(m2[j], tmax[j]);
                float al = exp2f(m2[j] - mnew);
                m2[j] = mnew;
                lrow[j] *= al;
                #pragma unroll
                for (int n = 0; n < 4; ++n) oacc[n][j] *= al;
            }
        }
        #pragma unroll
        for (int j = 0; j < 4; ++j) {
            float ts = 0.f;
            #pragma unroll
            for (int n = 0; n < 4; ++n) {
                float pe = exp2f(s[n][j] - m2[j]);
                s[n][j] = pe;
                ts += pe;
            }
            if (!half) {
                #pragma unroll
                for (int n = 4; n < 8; ++n) {
                    float pe = exp2f(s[n][j] - m2[j]);
                    s[n][j] = pe;
                    ts += pe;
                }
            }
            #pragma unroll
            for (int mm = 1; mm <= 8; mm <<= 1) ts += __shfl_xor(ts, mm);
            lrow[j] += ts;
        }
        #pragma unroll
        for (int n = 0; n < 4; ++n)
            #pragma unroll
            for (int j = 0; j < 4; ++j)
                P_lds[w][cc * 4 + j][n * 16 + r16] = f2bf(s[n][j]);
        if (!half) {
            #pragma unroll
            for (int n = 4; n < 8; ++n)
                #pragma unroll
                for (int j = 0; j < 4; ++j)
                    P_lds[w][cc * 4 + j][n * 16 + r16] = f2bf(s[n][j]);
        }
        short8 pa[4];
        pa[0] = *(const short8*)&P_lds[w][r16][cc * 8];
        pa[1] = *(const short8*)&P_lds[w][r16][32 + cc * 8];
        if (!half) {
            pa[2] = *(const short8*)&P_lds[w][r16][64 + cc * 8];
            pa[3] = *(const short8*)&P_lds[w][r16][96 + cc * 8];
        }
        __builtin_amdgcn_s_setprio(1);
        #pragma unroll
        for (int n = 0; n < 4; ++n) {
            #pragma unroll
            for (int qq = 0; qq < 2; ++qq) {
                short8 bv = *(const short8*)&VT_lds[n * 16 + r16][qq * 32 + cc * 8];
                oacc[n] = mfma_bf16(pa[qq], bv, oacc[n]);
            }
        }
        __builtin_amdgcn_s_setprio(0);
        if (!half) {
            __builtin_amdgcn_s_setprio(1);
            #pragma unroll
            for (int n = 0; n < 4; ++n) {
                #pragma unroll
                for (int qq = 2; qq < 4; ++qq) {
                    short8 bv = *(const short8*)&VT_lds[n * 16 + r16][qq * 32 + cc * 8];
                    oacc[n] = mfma_bf16(pa[qq], bv, oacc[n]);
                }
            }
            __builtin_amdgcn_s_setprio(0);
        }
        __syncthreads();
    }
    float rl[4];
    #pragma unroll
    for (int j = 0; j < 4; ++j) rl[j] = 1.0f / lrow[j];
    #pragma unroll
    for (int n = 0; n < 4; ++n)
        #pragma unroll
        for (int j = 0; j < 4; ++j) {
            int row = qbase + w * 16 + cc * 4 + j;
            o[obase + (size_t)row * EDIM + n * 16 + r16] = f2bf(oacc[n][j] * rl[j]);
        }
}

extern "C" void kernel_launch(void* const* d_in, const int* in_sizes, int n_in,
                              void* d_out, int out_size, void* d_ws, size_t ws_size,
                              hipStream_t stream) {
    const int*   idx     = (const int*)d_in[0];
    const float* tok_emb = (const float*)d_in[1];
    const float* pos_emb = (const float*)d_in[2];
    const float* Wq      = (const float*)d_in[3];
    const float* Wk      = (const float*)d_in[4];
    const float* Wv      = (const float*)d_in[5];
    const float* Wo      = (const float*)d_in[6];
    const float* bo      = (const float*)d_in[7];
    const float* ln1_s   = (const float*)d_in[8];
    const float* ln1_b   = (const float*)d_in[9];
    const float* W1      = (const float*)d_in[10];
    const float* b1      = (const float*)d_in[11];
    const float* W2      = (const float*)d_in[12];
    const float* b2      = (const float*)d_in[13];
    const float* ln2_s   = (const float*)d_in[14];
    const float* ln2_b   = (const float*)d_in[15];
    const float* lnf_s   = (const float*)d_in[16];
    const float* lnf_b   = (const float*)d_in[17];
    const float* lm_w    = (const float*)d_in[18];
    const float* lm_b    = (const float*)d_in[19];
    float* out = (float*)d_out;

    const size_t MB = 1 << 20;
    char* ws = (char*)d_ws;
    float*          x    = (float*)ws;                                  // 0..8 MB
    unsigned short* h    = (unsigned short*)(ws + 8 * MB);              // 8..12
    unsigned short* qkv  = (unsigned short*)(ws + 12 * MB);             // 12..24
    unsigned short* ao   = (unsigned short*)(ws + 24 * MB);             // 24..28
    unsigned short* ff   = (unsigned short*)(ws + 28 * MB);             // 28..44
    unsigned short* qkvT = (unsigned short*)(ws + 44 * MB);             // 44..50
    unsigned short* woT  = (unsigned short*)(ws + 50 * MB);             // 50..52
    unsigned short* w1T  = (unsigned short*)(ws + 52 * MB);             // 52..60
    unsigned short* w2Ta = (unsigned short*)(ws + 60 * MB);             // 60..68
    unsigned short* lmT  = (unsigned short*)(ws + 68 * MB);             // 68..130.5

    bool tier1 = ws_size >= (size_t)140 * MB;
    bool tier2 = ws_size >= (size_t)172 * MB;
    unsigned short* w2Tb = tier1 ? (unsigned short*)(ws + 131 * MB) : w2Ta;
    unsigned short* part = (unsigned short*)(ws + (tier2 ? (size_t)139 * MB : (size_t)68 * MB));

    dim3 blk(256);
    embed_ln_kernel<<<MROWS, blk, 0, stream>>>(idx, tok_emb, pos_emb, x, ln1_s, ln1_b, h);
    wconv_layer_kernel<<<3072, blk, 0, stream>>>(Wq, Wk, Wv, Wo, W1, W2,
                                                 qkvT, woT, w1T, w2Ta);

    for (int l = 0; l < NLAYERS; ++l) {
        unsigned short* w2cur = (l & 1) ? w2Tb : w2Ta;
        unsigned short* w2nxt = ((l + 1) & 1) ? w2Tb : w2Ta;
        size_t eo1 = (size_t)(l + 1) * EDIM * EDIM;

        // QKV: M2048 N3072 K1024 -> 16x24 = 384 wg
        gemm128<0><<<dim3(384, 1), blk, 0, stream>>>(h, qkvT, qkv, QKVN, EDIM, 24, 384, EDIM);
        attn_kernel<<<dim3(TSEQ / 64, NHEADS, NBATCH), blk, 0, stream>>>(qkv, ao);
        // Wo: N1024 K1024, 16x8 = 128 wg x kz4 (kspan 256), bf16 partials
        gemm128<4><<<dim3(128, 4), blk, 0, stream>>>(ao, woT, part, EDIM, EDIM, 8, 128, 256);
        reduce_ln_kernel<4><<<MROWS, blk, 0, stream>>>(part, bo + l * EDIM, x, ln2_s + l * EDIM, ln2_b + l * EDIM, h);
        // FF1: M2048 N4096 K1024 -> 3-buffer pipeline, 256 wg of 512 thr
        gemm_p3<2><<<dim3(256, 1), dim3(512), 0, stream>>>(h, w1T, b1 + l * FFDIM, nullptr, ff, FFDIM, EDIM, 16, 16);
        // FF2 (+ overlapped weight conversion for next layer / lm head)
        if (l < NLAYERS - 1) {
            if (tier1)
                ff2_fused_kernel<0><<<3584, blk, 0, stream>>>(
                    ff, w2cur, part,
                    Wq + eo1, Wk + eo1, Wv + eo1, Wo + eo1,
                    W1 + (size_t)(l + 1) * EDIM * FFDIM, W2 + (size_t)(l + 1) * FFDIM * EDIM,
                    nullptr, qkvT, woT, w1T, w2nxt, nullptr);
            else {
                gemm128<4><<<dim3(128, 4), blk, 0, stream>>>(ff, w2cur, part, EDIM, FFDIM, 8, 128, 1024);
                wconv_layer_kernel<<<3072, blk, 0, stream>>>(
                    Wq + eo1, Wk + eo1, Wv + eo1, Wo + eo1,
                    W1 + (size_t)(l + 1) * EDIM * FFDIM, W2 + (size_t)(l + 1) * FFDIM * EDIM,
                    qkvT, woT, w1T, w2nxt);
            }
        } else {
            if (tier2)
                ff2_fused_kernel<1><<<8512, blk, 0, stream>>>(
                    ff, w2cur, part,
                    nullptr, nullptr, nullptr, nullptr, nullptr, nullptr,
                    lm_w, nullptr, nullptr, nullptr, nullptr, lmT);
            else
                gemm128<4><<<dim3(128, 4), blk, 0, stream>>>(ff, w2cur, part, EDIM, FFDIM, 8, 128, 1024);
        }
        if (l < NLAYERS - 1)
            reduce_ln_kernel<4><<<MROWS, blk, 0, stream>>>(part, b2 + l * EDIM, x, ln1_s + (l + 1) * EDIM, ln1_b + (l + 1) * EDIM, h);
        else
            reduce_ln_kernel<4><<<MROWS, blk, 0, stream>>>(part, b2 + l * EDIM, x, lnf_s, lnf_b, h);
    }
    if (!tier2)
        wconv_kernel<<<dim3(16, 500), blk, 0, stream>>>(lm_w, lmT, EDIM, VOCAB);
    // lm head: N32000 K1024, 16m x 125n (n-major) = 2000 wg
    gemm_wide_lm<<<dim3(2000, 1), blk, 0, stream>>>(h, lmT, lm_b, out, VOCAB, EDIM, 16, 125);
}

// Round 11
// 1382.106 us; speedup vs baseline: 1.0561x; 1.0327x over previous
//
#include <hip/hip_runtime.h>

#define EDIM 1024
#define NHEADS 16
#define HDIM 64
#define TSEQ 1024
#define NBATCH 2
#define MROWS 2048
#define FFDIM 4096
#define NLAYERS 8
#define VOCAB 32000
#define QKVN 3072
#define SC2 0.18033688011112042f   /* 0.125 * log2(e) */

typedef __attribute__((ext_vector_type(4))) float f32x4;
typedef __attribute__((ext_vector_type(8))) short short8;

__device__ __forceinline__ unsigned short f2bf(float f) {
    union { float f; unsigned u; } v; v.f = f;
    unsigned r = v.u + 0x7fffu + ((v.u >> 16) & 1u);
    return (unsigned short)(r >> 16);
}

__device__ __forceinline__ float bf2f(unsigned u) {
    union { unsigned u; float f; } v; v.u = u << 16; return v.f;
}

__device__ __forceinline__ f32x4 mfma_bf16(short8 a, short8 b, f32x4 c) {
    return __builtin_amdgcn_mfma_f32_16x16x32_bf16(a, b, c, 0, 0, 0);
}

// tanh-form gelu (max abs dev from exact erf-gelu ~3e-4)
__device__ __forceinline__ float gelu_t(float x) {
    float u = 0.7978845608028654f * (x + 0.044715f * x * x * x);
    float t = exp2f(-2.885390081777927f * fabsf(u));   // e^{-2|u|}
    float th = (1.0f - t) / (1.0f + t);
    th = u < 0.0f ? -th : th;
    return 0.5f * x * (1.0f + th);
}

// async global->LDS, 16B per lane; LDS dest = wave-uniform base + lane*16
__device__ __forceinline__ void gload16(const unsigned short* g, unsigned short* l) {
    __builtin_amdgcn_global_load_lds(
        (const __attribute__((address_space(1))) unsigned int*)g,
        (__attribute__((address_space(3))) unsigned int*)l, 16, 0, 0);
}

// ---------------- LN core ----------------
__device__ __forceinline__ void ln_store(
    f32x4 v, int tid, const float* __restrict__ sc, const float* __restrict__ bi,
    unsigned short* __restrict__ hrow)
{
    float sum = v[0] + v[1] + v[2] + v[3];
    float sq = v[0]*v[0] + v[1]*v[1] + v[2]*v[2] + v[3]*v[3];
    #pragma unroll
    for (int m = 1; m <= 32; m <<= 1) { sum += __shfl_xor(sum, m); sq += __shfl_xor(sq, m); }
    __shared__ float sh[8];
    int w = tid >> 6;
    if ((tid & 63) == 0) { sh[w] = sum; sh[4 + w] = sq; }
    __syncthreads();
    sum = sh[0] + sh[1] + sh[2] + sh[3];
    sq  = sh[4] + sh[5] + sh[6] + sh[7];
    float mu = sum * (1.0f / EDIM);
    float inv = rsqrtf(sq * (1.0f / EDIM) - mu * mu + 1e-5f);
    int c = tid * 4;
    unsigned o0 = (unsigned)f2bf((v[0] - mu) * inv * sc[c + 0] + bi[c + 0])
                | ((unsigned)f2bf((v[1] - mu) * inv * sc[c + 1] + bi[c + 1]) << 16);
    unsigned o1 = (unsigned)f2bf((v[2] - mu) * inv * sc[c + 2] + bi[c + 2])
                | ((unsigned)f2bf((v[3] - mu) * inv * sc[c + 3] + bi[c + 3]) << 16);
    unsigned* hp = (unsigned*)(hrow + c);
    hp[0] = o0; hp[1] = o1;
}

// fused: x += bias + sum_kz part(bf16);  h = LN(x)
template<int KZ>
__global__ __launch_bounds__(256) void reduce_ln_kernel(
    const unsigned short* __restrict__ part, const float* __restrict__ bias,
    float* __restrict__ x, const float* __restrict__ sc,
    const float* __restrict__ bi, unsigned short* __restrict__ h)
{
    int row = blockIdx.x, tid = threadIdx.x;
    int c = tid * 4;
    f32x4 s = *(const f32x4*)(x + (size_t)row * EDIM + c);
    s += *(const f32x4*)(bias + c);
    #pragma unroll
    for (int kz = 0; kz < KZ; ++kz) {
        const unsigned* p = (const unsigned*)(part + ((size_t)kz * MROWS + row) * EDIM + c);
        unsigned p0 = p[0], p1 = p[1];
        s[0] += bf2f(p0); s[1] += bf2f(p0 >> 16);
        s[2] += bf2f(p1); s[3] += bf2f(p1 >> 16);
    }
    *(f32x4*)(x + (size_t)row * EDIM + c) = s;
    ln_store(s, tid, sc, bi, h + (size_t)row * EDIM);
}

// ---------------- weight convert+transpose tile (64x64), LDS passed in ----------
__device__ __forceinline__ void conv_tile(
    unsigned short* __restrict__ Tb,   // >= 64*72 shorts
    const float* __restrict__ W, unsigned short* __restrict__ WT,
    int Kdim, int Ndim, int k0, int n0, int tid)
{
    int r = tid >> 4, c4 = (tid & 15) * 4;
    #pragma unroll
    for (int i = 0; i < 4; ++i) {
        f32x4 v = *(const f32x4*)(W + (size_t)(k0 + r + 16 * i) * Ndim + n0 + c4);
        Tb[(c4 + 0) * 72 + r + 16 * i] = f2bf(v[0]);
        Tb[(c4 + 1) * 72 + r + 16 * i] = f2bf(v[1]);
        Tb[(c4 + 2) * 72 + r + 16 * i] = f2bf(v[2]);
        Tb[(c4 + 3) * 72 + r + 16 * i] = f2bf(v[3]);
    }
    __syncthreads();
    int nr = tid >> 2, kc = (tid & 3) * 16;
    short8 o0 = *(const short8*)&Tb[nr * 72 + kc];
    short8 o1 = *(const short8*)&Tb[nr * 72 + kc + 8];
    *(short8*)(WT + (size_t)(n0 + nr) * Kdim + k0 + kc)     = o0;
    *(short8*)(WT + (size_t)(n0 + nr) * Kdim + k0 + kc + 8) = o1;
}

// conv dispatcher over one layer's 6 weights; t in [0, 3072)
__device__ __forceinline__ void wconv_layer_body(
    unsigned short* Tb, int t, int tid,
    const float* Wq, const float* Wk, const float* Wv, const float* Wo,
    const float* W1, const float* W2,
    unsigned short* qkvT, unsigned short* woT,
    unsigned short* w1T, unsigned short* w2T)
{
    if (t < 768) {
        int wsel = t >> 8, tt = t & 255;
        const float* src = wsel == 0 ? Wq : (wsel == 1 ? Wk : Wv);
        conv_tile(Tb, src, qkvT + (size_t)wsel * EDIM * EDIM, EDIM, EDIM,
                  (tt & 15) * 64, (tt >> 4) * 64, tid);
    } else if (t < 1024) {
        int tt = t - 768;
        conv_tile(Tb, Wo, woT, EDIM, EDIM, (tt & 15) * 64, (tt >> 4) * 64, tid);
    } else if (t < 2048) {
        int tt = t - 1024;
        conv_tile(Tb, W1, w1T, EDIM, FFDIM, (tt & 15) * 64, (tt >> 4) * 64, tid);
    } else {
        int tt = t - 2048;
        conv_tile(Tb, W2, w2T, FFDIM, EDIM, (tt >> 4) * 64, (tt & 15) * 64, tid);
    }
}

__global__ __launch_bounds__(256) void wconv_layer_kernel(
    const float* __restrict__ Wq, const float* __restrict__ Wk,
    const float* __restrict__ Wv, const float* __restrict__ Wo,
    const float* __restrict__ W1, const float* __restrict__ W2,
    unsigned short* __restrict__ qkvT, unsigned short* __restrict__ woT,
    unsigned short* __restrict__ w1T, unsigned short* __restrict__ w2T)
{
    __shared__ __align__(16) unsigned short Tb[64 * 72];
    wconv_layer_body(Tb, blockIdx.x, threadIdx.x, Wq, Wk, Wv, Wo, W1, W2,
                     qkvT, woT, w1T, w2T);
}

__global__ __launch_bounds__(256) void wconv_kernel(
    const float* __restrict__ W, unsigned short* __restrict__ WT, int Kdim, int Ndim)
{
    __shared__ __align__(16) unsigned short Tb[64 * 72];
    conv_tile(Tb, W, WT, Kdim, Ndim, blockIdx.x * 64, blockIdx.y * 64, threadIdx.x);
}

// ---------------- fused embed+LN (blocks 0..2047) + layer-0 wconv (2048..5119) -----
__global__ __launch_bounds__(256) void embed_wconv_kernel(
    const int* __restrict__ idx, const float* __restrict__ tok,
    const float* __restrict__ pos, float* __restrict__ x,
    const float* __restrict__ sc, const float* __restrict__ bi,
    unsigned short* __restrict__ h,
    const float* __restrict__ Wq, const float* __restrict__ Wk,
    const float* __restrict__ Wv, const float* __restrict__ Wo,
    const float* __restrict__ W1, const float* __restrict__ W2,
    unsigned short* __restrict__ qkvT, unsigned short* __restrict__ woT,
    unsigned short* __restrict__ w1T, unsigned short* __restrict__ w2T)
{
    __shared__ __align__(16) unsigned short Tb[64 * 72];
    int bid = blockIdx.x, tid = threadIdx.x;
    if (bid < MROWS) {
        int row = bid;
        int t = row & (TSEQ - 1);
        int tokid = idx[row];
        int c = tid * 4;
        f32x4 a = *(const f32x4*)(tok + (size_t)tokid * EDIM + c);
        f32x4 b = *(const f32x4*)(pos + (size_t)t * EDIM + c);
        f32x4 v = a + b;
        *(f32x4*)(x + (size_t)row * EDIM + c) = v;
        ln_store(v, tid, sc, bi, h + (size_t)row * EDIM);
    } else {
        wconv_layer_body(Tb, bid - MROWS, tid, Wq, Wk, Wv, Wo, W1, W2,
                         qkvT, woT, w1T, w2T);
    }
}

// ---------------- narrow GEMM body: block 128x128, 4 waves, BK=64, XOR-swizzle ----
// EPI 0: ->bf16   4: partial bf16 (split-K, Cb indexed by kz)
template<int EPI>
__device__ __forceinline__ void gemm128_body(
    unsigned short* SMEM,   // >= 16384 shorts (A 8192 | B 8192)
    const unsigned short* __restrict__ A, const unsigned short* __restrict__ WT,
    unsigned short* __restrict__ Cb,
    int Ndim, int Kdim, int ntiles, int nwg, int kspan, int bid, int kz)
{
    unsigned short* A_lds = SMEM;
    unsigned short* B_lds = SMEM + 8192;
    int tid = threadIdx.x;
    int q8 = nwg >> 3;
    int swz = (bid & 7) * q8 + (bid >> 3);
    int bm0 = (swz / ntiles) * 128, bn0 = (swz % ntiles) * 128;
    int lane = tid & 63, w = tid >> 6;
    int wr = w >> 1, wc = w & 1;
    int r16 = lane & 15, cc = lane >> 4;
    int lrow = lane >> 3;
    int lcol = ((lane & 7) ^ lrow) * 8;
    int sw = r16 & 7;

    f32x4 acc[4][4];
    #pragma unroll
    for (int m = 0; m < 4; ++m)
        #pragma unroll
        for (int n = 0; n < 4; ++n) acc[m][n] = {0.f, 0.f, 0.f, 0.f};

    int kbeg = kz * kspan, kend = kbeg + kspan;
    for (int k0 = kbeg; k0 < kend; k0 += 64) {
        #pragma unroll
        for (int i = 0; i < 4; ++i) {
            int c = i * 4 + w;
            gload16(A + (size_t)(bm0 + c * 8 + lrow) * Kdim + k0 + lcol, A_lds + c * 512);
            gload16(WT + (size_t)(bn0 + c * 8 + lrow) * Kdim + k0 + lcol, B_lds + c * 512);
        }
        __syncthreads();
        #pragma unroll
        for (int kh = 0; kh < 2; ++kh) {
            short8 af[4], bfr[4];
            #pragma unroll
            for (int m = 0; m < 4; ++m)
                af[m] = *(const short8*)&A_lds[(wr * 64 + m * 16 + r16) * 64 + ((kh * 4 + cc) ^ sw) * 8];
            #pragma unroll
            for (int n = 0; n < 4; ++n)
                bfr[n] = *(const short8*)&B_lds[(wc * 64 + n * 16 + r16) * 64 + ((kh * 4 + cc) ^ sw) * 8];
            #pragma unroll
            for (int m = 0; m < 4; ++m)
                #pragma unroll
                for (int n = 0; n < 4; ++n)
                    acc[m][n] = mfma_bf16(af[m], bfr[n], acc[m][n]);
        }
        __syncthreads();
    }

    #pragma unroll
    for (int m = 0; m < 4; ++m) {
        #pragma unroll
        for (int n = 0; n < 4; ++n) {
            #pragma unroll
            for (int j = 0; j < 4; ++j) {
                int row = bm0 + wr * 64 + m * 16 + cc * 4 + j;
                int col = bn0 + wc * 64 + n * 16 + r16;
                float vv = acc[m][n][j];
                if constexpr (EPI == 0)
                    Cb[(size_t)row * Ndim + col] = f2bf(vv);
                else
                    Cb[((size_t)kz * MROWS + row) * Ndim + col] = f2bf(vv);
            }
        }
    }
}

template<int EPI>
__global__ __launch_bounds__(256, 3) void gemm128(
    const unsigned short* __restrict__ A, const unsigned short* __restrict__ WT,
    unsigned short* __restrict__ Cb,
    int Ndim, int Kdim, int ntiles, int nwg, int kspan)
{
    __shared__ __align__(16) unsigned short SMEM[16384];
    gemm128_body<EPI>(SMEM, A, WT, Cb, Ndim, Kdim, ntiles, nwg, kspan,
                      blockIdx.x, blockIdx.y);
}

// ---------------- fused FF2 (split-K4, bf16 partials) + weight conversion ----------
template<int MODE>
__global__ __launch_bounds__(256, 3) void ff2_fused_kernel(
    const unsigned short* __restrict__ A, const unsigned short* __restrict__ WT,
    unsigned short* __restrict__ Cp,
    const float* __restrict__ Wq, const float* __restrict__ Wk,
    const float* __restrict__ Wv, const float* __restrict__ Wo,
    const float* __restrict__ W1, const float* __restrict__ W2,
    const float* __restrict__ lmW,
    unsigned short* __restrict__ qkvT, unsigned short* __restrict__ woT,
    unsigned short* __restrict__ w1T, unsigned short* __restrict__ w2Tn,
    unsigned short* __restrict__ lmT)
{
    __shared__ __align__(16) unsigned short SMEM[16384];
    int bid = blockIdx.x;
    if (bid < 512) {
        gemm128_body<4>(SMEM, A, WT, Cp, EDIM, FFDIM, 8, 128, 1024,
                        bid & 127, bid >> 7);
    } else if constexpr (MODE == 0) {
        wconv_layer_body(SMEM, bid - 512, threadIdx.x, Wq, Wk, Wv, Wo, W1, W2,
                         qkvT, woT, w1T, w2Tn);
    } else {
        int t = bid - 512;
        conv_tile(SMEM, lmW, lmT, EDIM, VOCAB, (t & 15) * 64, (t >> 4) * 64, threadIdx.x);
    }
}

// ---------------- 3-buffer counted-vmcnt GEMM: 512 thr, 8 waves, 128x256 -----------
// EPI 2: +bias, gelu -> bf16 (FF1)    EPI 5: scale Q cols -> bf16 (QKV, no bias)
template<int EPI>
__global__ __launch_bounds__(512, 2) void gemm_p3(
    const unsigned short* __restrict__ A, const unsigned short* __restrict__ WT,
    const float* __restrict__ bias, float* __restrict__ Cf,
    unsigned short* __restrict__ Cb, int Ndim, int Kdim, int mtiles, int ntiles)
{
    __shared__ __align__(16) unsigned short LDS[3][24576];  // per buf: A 16KB | B 32KB
    const int tid = threadIdx.x;
    const int nwg = mtiles * ntiles, q8 = nwg >> 3;
    const int swz = (int)(blockIdx.x & 7) * q8 + (int)(blockIdx.x >> 3);
    const int bn0 = (swz / mtiles) * 256, bm0 = (swz % mtiles) * 128;   // n-major
    const int lane = tid & 63, w = tid >> 6;
    const int wr = w >> 2, wc = w & 3;
    const int r16 = lane & 15, cc = lane >> 4;
    const int lrow = lane >> 3;
    const int lcol = ((lane & 7) ^ lrow) * 8;
    const int sw = r16 & 7;

    f32x4 acc[4][4];
    #pragma unroll
    for (int m = 0; m < 4; ++m)
        #pragma unroll
        for (int n = 0; n < 4; ++n) acc[m][n] = {0.f, 0.f, 0.f, 0.f};

    const int nk = Kdim >> 6;

    auto STAGE = [&](int t, int bufidx) {
        int k0 = t * 64;
        unsigned short* buf = &LDS[bufidx][0];
        #pragma unroll
        for (int i = 0; i < 2; ++i) {
            int c = i * 8 + w;
            gload16(A + (size_t)(bm0 + c * 8 + lrow) * Kdim + k0 + lcol, buf + c * 512);
        }
        #pragma unroll
        for (int i = 0; i < 4; ++i) {
            int c = i * 8 + w;
            gload16(WT + (size_t)(bn0 + c * 8 + lrow) * Kdim + k0 + lcol, buf + 8192 + c * 512);
        }
    };

    STAGE(0, 0);
    STAGE(1, 1);
    asm volatile("s_waitcnt vmcnt(6)" ::: "memory");
    __builtin_amdgcn_sched_barrier(0);
    __builtin_amdgcn_s_barrier();
    __builtin_amdgcn_sched_barrier(0);

    int cur = 0;
    for (int t = 0; t < nk; ++t) {
        if (t + 2 < nk) STAGE(t + 2, cur == 0 ? 2 : cur - 1);
        const unsigned short* Abuf = &LDS[cur][0];
        const unsigned short* Bbuf = &LDS[cur][8192];
        #pragma unroll
        for (int kh = 0; kh < 2; ++kh) {
            short8 af[4], bfr[4];
            #pragma unroll
            for (int m = 0; m < 4; ++m)
                af[m] = *(const short8*)&Abuf[(wr * 64 + m * 16 + r16) * 64 + ((kh * 4 + cc) ^ sw) * 8];
            #pragma unroll
            for (int n = 0; n < 4; ++n)
                bfr[n] = *(const short8*)&Bbuf[(wc * 64 + n * 16 + r16) * 64 + ((kh * 4 + cc) ^ sw) * 8];
            __builtin_amdgcn_s_setprio(1);
            #pragma unroll
            for (int m = 0; m < 4; ++m)
                #pragma unroll
                for (int n = 0; n < 4; ++n)
                    acc[m][n] = mfma_bf16(af[m], bfr[n], acc[m][n]);
            __builtin_amdgcn_s_setprio(0);
        }
        if (t + 1 < nk) {
            if (t + 2 < nk) asm volatile("s_waitcnt vmcnt(6)" ::: "memory");
            else            asm volatile("s_waitcnt vmcnt(0)" ::: "memory");
            __builtin_amdgcn_sched_barrier(0);
            __builtin_amdgcn_s_barrier();
            __builtin_amdgcn_sched_barrier(0);
            asm volatile("" ::: "memory");
        }
        cur = cur == 2 ? 0 : cur + 1;
    }

    #pragma unroll
    for (int m = 0; m < 4; ++m) {
        #pragma unroll
        for (int n = 0; n < 4; ++n) {
            #pragma unroll
            for (int j = 0; j < 4; ++j) {
                int row = bm0 + wr * 64 + m * 16 + cc * 4 + j;
                int col = bn0 + wc * 64 + n * 16 + r16;
                float vv = acc[m][n][j];
                if constexpr (EPI == 2) {
                    vv += bias[col];
                    Cb[(size_t)row * Ndim + col] = f2bf(gelu_t(vv));
                } else if constexpr (EPI == 5) {
                    if (col < EDIM) vv *= SC2;     // pre-scale Q for attention
                    Cb[(size_t)row * Ndim + col] = f2bf(vv);
                } else {
                    Cf[(size_t)row * Ndim + col] = vv + bias[col];
                }
            }
        }
    }
}

// ---------------- wide GEMM (lm head): block 128Mx256N, wave 64x128, n-major -------
__global__ __launch_bounds__(256, 2) void gemm_wide_lm(
    const unsigned short* __restrict__ A, const unsigned short* __restrict__ WT,
    const float* __restrict__ bias, float* __restrict__ Cf,
    int Ndim, int Kdim, int mtiles, int ntiles)
{
    __shared__ __align__(16) unsigned short A_lds[128][64];
    __shared__ __align__(16) unsigned short B_lds[256][64];
    int tid = threadIdx.x;
    int nwg = mtiles * ntiles;
    int q8 = nwg >> 3;
    int swz = (int)(blockIdx.x & 7) * q8 + (int)(blockIdx.x >> 3);
    int bn0 = (swz / mtiles) * 256, bm0 = (swz % mtiles) * 128;
    int lane = tid & 63, w = tid >> 6;
    int wr = w >> 1, wc = w & 1;
    int r16 = lane & 15, cc = lane >> 4;
    int lrow = lane >> 3;
    int lcol = ((lane & 7) ^ lrow) * 8;
    int sw = r16 & 7;

    f32x4 acc[4][8];
    #pragma unroll
    for (int m = 0; m < 4; ++m)
        #pragma unroll
        for (int n = 0; n < 8; ++n) acc[m][n] = {0.f, 0.f, 0.f, 0.f};

    for (int k0 = 0; k0 < Kdim; k0 += 64) {
        #pragma unroll
        for (int i = 0; i < 4; ++i) {
            int c = i * 4 + w;
            gload16(A + (size_t)(bm0 + c * 8 + lrow) * Kdim + k0 + lcol,
                    (unsigned short*)A_lds + c * 512);
        }
        #pragma unroll
        for (int i = 0; i < 8; ++i) {
            int c = i * 4 + w;
            gload16(WT + (size_t)(bn0 + c * 8 + lrow) * Kdim + k0 + lcol,
                    (unsigned short*)B_lds + c * 512);
        }
        __syncthreads();
        #pragma unroll
        for (int kh = 0; kh < 2; ++kh) {
            short8 af[4], bfr[8];
            #pragma unroll
            for (int m = 0; m < 4; ++m)
                af[m] = *(const short8*)&A_lds[wr * 64 + m * 16 + r16][((kh * 4 + cc) ^ sw) * 8];
            #pragma unroll
            for (int n = 0; n < 8; ++n)
                bfr[n] = *(const short8*)&B_lds[wc * 128 + n * 16 + r16][((kh * 4 + cc) ^ sw) * 8];
            #pragma unroll
            for (int m = 0; m < 4; ++m)
                #pragma unroll
                for (int n = 0; n < 8; ++n)
                    acc[m][n] = mfma_bf16(af[m], bfr[n], acc[m][n]);
        }
        __syncthreads();
    }

    #pragma unroll
    for (int m = 0; m < 4; ++m) {
        #pragma unroll
        for (int n = 0; n < 8; ++n) {
            #pragma unroll
            for (int j = 0; j < 4; ++j) {
                int row = bm0 + wr * 64 + m * 16 + cc * 4 + j;
                int col = bn0 + wc * 128 + n * 16 + r16;
                Cf[(size_t)row * Ndim + col] = acc[m][n][j] + bias[col];
            }
        }
    }
}

// ---------------- flash attention: KVBLK=128, Q pre-scaled, diag-specialized -------
__global__ __launch_bounds__(256) void attn_kernel(
    const unsigned short* __restrict__ qkv, unsigned short* __restrict__ o)
{
    __shared__ __align__(16) unsigned short K_lds[128][72];
    __shared__ __align__(16) unsigned short VT_lds[64][136];
    __shared__ __align__(16) unsigned short P_lds[4][16][136];

    int qt = (int)gridDim.x - 1 - (int)blockIdx.x;   // longest blocks first
    int head = blockIdx.y, bb = blockIdx.z;
    int tid = threadIdx.x, w = tid >> 6, lane = tid & 63;
    int r16 = lane & 15, cc = lane >> 4;
    size_t base = ((size_t)bb * TSEQ) * QKVN + head * HDIM;
    const unsigned short* q = qkv + base;
    const unsigned short* k = qkv + base + EDIM;
    const unsigned short* v = qkv + base + 2 * EDIM;
    size_t obase = ((size_t)bb * TSEQ) * EDIM + head * HDIM;
    int qbase = qt * 64;

    const unsigned short* qp = q + (size_t)(qbase + w * 16 + r16) * QKVN;
    short8 aq0 = *(const short8*)(qp + cc * 8);
    short8 aq1 = *(const short8*)(qp + 32 + cc * 8);

    f32x4 oacc[4];
    float m2[4], lrow[4];
    #pragma unroll
    for (int n = 0; n < 4; ++n) oacc[n] = {0.f, 0.f, 0.f, 0.f};
    #pragma unroll
    for (int j = 0; j < 4; ++j) { m2[j] = -1e30f; lrow[j] = 0.f; }

    int krow = tid >> 1, kch = (tid & 1) * 32;
    int vk2 = (tid & 63) * 2, vdb = (tid >> 6) * 16;
    int myrow = qbase + w * 16 + cc * 4;

    int nkt = (qt + 2) >> 1;
    for (int kt = 0; kt < nkt; ++kt) {
        int kbase = kt * 128;
        bool last = (kt == nkt - 1);
        bool half = last && !(qt & 1);    // frags 4..7 fully masked -> dead
        if (!half || krow < 64) {
            const unsigned short* kp = k + (size_t)(kbase + krow) * QKVN + kch;
            *(short8*)&K_lds[krow][kch]      = *(const short8*)kp;
            *(short8*)&K_lds[krow][kch + 8]  = *(const short8*)(kp + 8);
            *(short8*)&K_lds[krow][kch + 16] = *(const short8*)(kp + 16);
            *(short8*)&K_lds[krow][kch + 24] = *(const short8*)(kp + 24);
        }
        if (!half || vk2 < 64) {
            const unsigned short* vp0 = v + (size_t)(kbase + vk2) * QKVN + vdb;
            short8 v0a = *(const short8*)vp0;
            short8 v0b = *(const short8*)(vp0 + 8);
            short8 v1a = *(const short8*)(vp0 + QKVN);
            short8 v1b = *(const short8*)(vp0 + QKVN + 8);
            #pragma unroll
            for (int i = 0; i < 8; ++i) {
                *(unsigned*)&VT_lds[vdb + i][vk2] =
                    (unsigned)(unsigned short)v0a[i] | ((unsigned)(unsigned short)v1a[i] << 16);
                *(unsigned*)&VT_lds[vdb + 8 + i][vk2] =
                    (unsigned)(unsigned short)v0b[i] | ((unsigned)(unsigned short)v1b[i] << 16);
            }
        }
        __syncthreads();

        f32x4 s[8];
        __builtin_amdgcn_s_setprio(1);
        #pragma unroll
        for (int n = 0; n < 4; ++n) {
            short8 bk0 = *(const short8*)&K_lds[n * 16 + r16][cc * 8];
            short8 bk1 = *(const short8*)&K_lds[n * 16 + r16][32 + cc * 8];
            f32x4 z = {0.f, 0.f, 0.f, 0.f};
            z = mfma_bf16(aq0, bk0, z);
            z = mfma_bf16(aq1, bk1, z);
            s[n] = z;
        }
        __builtin_amdgcn_s_setprio(0);
        if (!half) {
            __builtin_amdgcn_s_setprio(1);
            #pragma unroll
            for (int n = 4; n < 8; ++n) {
                short8 bk0 = *(const short8*)&K_lds[n * 16 + r16][cc * 8];
                short8 bk1 = *(const short8*)&K_lds[n * 16 + r16][32 + cc * 8];
                f32x4 z = {0.f, 0.f, 0.f, 0.f};
                z = mfma_bf16(aq0, bk0, z);
                z = mfma_bf16(aq1, bk1, z);
                s[n] = z;
            }
            __builtin_amdgcn_s_setprio(0);
        }

        // triangular mask, only on diagonal frags (Q pre-scaled; no scale pass)
        if (last) {
            int nlo = half ? 0 : 4;
            #pragma unroll
            for (int n = 0; n < 8; ++n) {
                if (n >= nlo && n < nlo + 4) {
                    int key = kbase + n * 16 + r16;
                    #pragma unroll
                    for (int j = 0; j < 4; ++j)
                        if (key > myrow + j) s[n][j] = -1e30f;
                }
            }
        }

        float tmax[4];
        #pragma unroll
        for (int j = 0; j < 4; ++j) {
            float tm = fmaxf(fmaxf(s[0][j], s[1][j]), fmaxf(s[2][j], s[3][j]));
            if (!half) tm = fmaxf(tm, fmaxf(fmaxf(s[4][j], s[5][j]), fmaxf(s[6][j], s[7][j])));
            #pragma unroll
            for (int mm = 1; mm <= 8; mm <<= 1) tm = fmaxf(tm, __shfl_xor(tm, mm));
            tmax[j] = tm;
        }
        bool defer = (tmax[0] - m2[0] <= 11.5f) && (tmax[1] - m2[1] <= 11.5f)
                  && (tmax[2] - m2[2] <= 11.5f) && (tmax[3] - m2[3] <= 11.5f);
        if (!__all(defer)) {
            #pragma unroll
            for (int j = 0; j < 4; ++j) {
                float mnew = fmaxf(m2[j], tmax[j]);
                float al = exp2f(m2[j] - mnew);
                m2[j] = mnew;
                lrow[j] *= al;
                #pragma unroll
                for (int n = 0; n < 4; ++n) oacc[n][j] *= al;
            }
        }
        #pragma unroll
        for (int j = 0; j < 4; ++j) {
            float ts = 0.f;
            #pragma unroll
            for (int n = 0; n < 4; ++n) {
                float pe = exp2f(s[n][j] - m2[j]);
                s[n][j] = pe;
                ts += pe;
            }
            if (!half) {
                #pragma unroll
                for (int n = 4; n < 8; ++n) {
                    float pe = exp2f(s[n][j] - m2[j]);
                    s[n][j] = pe;
                    ts += pe;
                }
            }
            #pragma unroll
            for (int mm = 1; mm <= 8; mm <<= 1) ts += __shfl_xor(ts, mm);
            lrow[j] += ts;
        }
        #pragma unroll
        for (int n = 0; n < 4; ++n)
            #pragma unroll
            for (int j = 0; j < 4; ++j)
                P_lds[w][cc * 4 + j][n * 16 + r16] = f2bf(s[n][j]);
        if (!half) {
            #pragma unroll
            for (int n = 4; n < 8; ++n)
                #pragma unroll
                for (int j = 0; j < 4; ++j)
                    P_lds[w][cc * 4 + j][n * 16 + r16] = f2bf(s[n][j]);
        }
        short8 pa[4];
        pa[0] = *(const short8*)&P_lds[w][r16][cc * 8];
        pa[1] = *(const short8*)&P_lds[w][r16][32 + cc * 8];
        if (!half) {
            pa[2] = *(const short8*)&P_lds[w][r16][64 + cc * 8];
            pa[3] = *(const short8*)&P_lds[w][r16][96 + cc * 8];
        }
        __builtin_amdgcn_s_setprio(1);
        #pragma unroll
        for (int n = 0; n < 4; ++n) {
            #pragma unroll
            for (int qq = 0; qq < 2; ++qq) {
                short8 bv = *(const short8*)&VT_lds[n * 16 + r16][qq * 32 + cc * 8];
                oacc[n] = mfma_bf16(pa[qq], bv, oacc[n]);
            }
        }
        __builtin_amdgcn_s_setprio(0);
        if (!half) {
            __builtin_amdgcn_s_setprio(1);
            #pragma unroll
            for (int n = 0; n < 4; ++n) {
                #pragma unroll
                for (int qq = 2; qq < 4; ++qq) {
                    short8 bv = *(const short8*)&VT_lds[n * 16 + r16][qq * 32 + cc * 8];
                    oacc[n] = mfma_bf16(pa[qq], bv, oacc[n]);
                }
            }
            __builtin_amdgcn_s_setprio(0);
        }
        __syncthreads();
    }
    float rl[4];
    #pragma unroll
    for (int j = 0; j < 4; ++j) rl[j] = 1.0f / lrow[j];
    #pragma unroll
    for (int n = 0; n < 4; ++n)
        #pragma unroll
        for (int j = 0; j < 4; ++j) {
            int row = qbase + w * 16 + cc * 4 + j;
            o[obase + (size_t)row * EDIM + n * 16 + r16] = f2bf(oacc[n][j] * rl[j]);
        }
}

extern "C" void kernel_launch(void* const* d_in, const int* in_sizes, int n_in,
                              void* d_out, int out_size, void* d_ws, size_t ws_size,
                              hipStream_t stream) {
    const int*   idx     = (const int*)d_in[0];
    const float* tok_emb = (const float*)d_in[1];
    const float* pos_emb = (const float*)d_in[2];
    const float* Wq      = (const float*)d_in[3];
    const float* Wk      = (const float*)d_in[4];
    const float* Wv      = (const float*)d_in[5];
    const float* Wo      = (const float*)d_in[6];
    const float* bo      = (const float*)d_in[7];
    const float* ln1_s   = (const float*)d_in[8];
    const float* ln1_b   = (const float*)d_in[9];
    const float* W1      = (const float*)d_in[10];
    const float* b1      = (const float*)d_in[11];
    const float* W2      = (const float*)d_in[12];
    const float* b2      = (const float*)d_in[13];
    const float* ln2_s   = (const float*)d_in[14];
    const float* ln2_b   = (const float*)d_in[15];
    const float* lnf_s   = (const float*)d_in[16];
    const float* lnf_b   = (const float*)d_in[17];
    const float* lm_w    = (const float*)d_in[18];
    const float* lm_b    = (const float*)d_in[19];
    float* out = (float*)d_out;

    const size_t MB = 1 << 20;
    char* ws = (char*)d_ws;
    float*          x    = (float*)ws;                                  // 0..8 MB
    unsigned short* h    = (unsigned short*)(ws + 8 * MB);              // 8..12
    unsigned short* qkv  = (unsigned short*)(ws + 12 * MB);             // 12..24
    unsigned short* ao   = (unsigned short*)(ws + 24 * MB);             // 24..28
    unsigned short* ff   = (unsigned short*)(ws + 28 * MB);             // 28..44
    unsigned short* qkvT = (unsigned short*)(ws + 44 * MB);             // 44..50
    unsigned short* woT  = (unsigned short*)(ws + 50 * MB);             // 50..52
    unsigned short* w1T  = (unsigned short*)(ws + 52 * MB);             // 52..60
    unsigned short* w2Ta = (unsigned short*)(ws + 60 * MB);             // 60..68
    unsigned short* lmT  = (unsigned short*)(ws + 68 * MB);             // 68..130.5

    bool tier1 = ws_size >= (size_t)140 * MB;
    bool tier2 = ws_size >= (size_t)172 * MB;
    unsigned short* w2Tb = tier1 ? (unsigned short*)(ws + 131 * MB) : w2Ta;
    unsigned short* part = (unsigned short*)(ws + (tier2 ? (size_t)139 * MB : (size_t)68 * MB));

    dim3 blk(256);
    embed_wconv_kernel<<<MROWS + 3072, blk, 0, stream>>>(
        idx, tok_emb, pos_emb, x, ln1_s, ln1_b, h,
        Wq, Wk, Wv, Wo, W1, W2, qkvT, woT, w1T, w2Ta);

    for (int l = 0; l < NLAYERS; ++l) {
        unsigned short* w2cur = (l & 1) ? w2Tb : w2Ta;
        unsigned short* w2nxt = ((l + 1) & 1) ? w2Tb : w2Ta;
        size_t eo1 = (size_t)(l + 1) * EDIM * EDIM;

        // QKV: M2048 N3072 K1024 -> 3-buffer pipeline, 16m x 12n = 192 wg of 512 thr
        gemm_p3<5><<<dim3(192, 1), dim3(512), 0, stream>>>(h, qkvT, nullptr, nullptr, qkv, QKVN, EDIM, 16, 12);
        attn_kernel<<<dim3(TSEQ / 64, NHEADS, NBATCH), blk, 0, stream>>>(qkv, ao);
        // Wo: N1024 K1024, 16x8 = 128 wg x kz4 (kspan 256), bf16 partials
        gemm128<4><<<dim3(128, 4), blk, 0, stream>>>(ao, woT, part, EDIM, EDIM, 8, 128, 256);
        reduce_ln_kernel<4><<<MROWS, blk, 0, stream>>>(part, bo + l * EDIM, x, ln2_s + l * EDIM, ln2_b + l * EDIM, h);
        // FF1: M2048 N4096 K1024 -> 3-buffer pipeline, 256 wg of 512 thr
        gemm_p3<2><<<dim3(256, 1), dim3(512), 0, stream>>>(h, w1T, b1 + l * FFDIM, nullptr, ff, FFDIM, EDIM, 16, 16);
        // FF2 (+ overlapped weight conversion for next layer / lm head)
        if (l < NLAYERS - 1) {
            if (tier1)
                ff2_fused_kernel<0><<<3584, blk, 0, stream>>>(
                    ff, w2cur, part,
                    Wq + eo1, Wk + eo1, Wv + eo1, Wo + eo1,
                    W1 + (size_t)(l + 1) * EDIM * FFDIM, W2 + (size_t)(l + 1) * FFDIM * EDIM,
                    nullptr, qkvT, woT, w1T, w2nxt, nullptr);
            else {
                gemm128<4><<<dim3(128, 4), blk, 0, stream>>>(ff, w2cur, part, EDIM, FFDIM, 8, 128, 1024);
                wconv_layer_kernel<<<3072, blk, 0, stream>>>(
                    Wq + eo1, Wk + eo1, Wv + eo1, Wo + eo1,
                    W1 + (size_t)(l + 1) * EDIM * FFDIM, W2 + (size_t)(l + 1) * FFDIM * EDIM,
                    qkvT, woT, w1T, w2nxt);
            }
        } else {
            if (tier2)
                ff2_fused_kernel<1><<<8512, blk, 0, stream>>>(
                    ff, w2cur, part,
                    nullptr, nullptr, nullptr, nullptr, nullptr, nullptr,
                    lm_w, nullptr, nullptr, nullptr, nullptr, lmT);
            else
                gemm128<4><<<dim3(128, 4), blk, 0, stream>>>(ff, w2cur, part, EDIM, FFDIM, 8, 128, 1024);
        }
        if (l < NLAYERS - 1)
            reduce_ln_kernel<4><<<MROWS, blk, 0, stream>>>(part, b2 + l * EDIM, x, ln1_s + (l + 1) * EDIM, ln1_b + (l + 1) * EDIM, h);
        else
            reduce_ln_kernel<4><<<MROWS, blk, 0, stream>>>(part, b2 + l * EDIM, x, lnf_s, lnf_b, h);
    }
    if (!tier2)
        wconv_kernel<<<dim3(16, 500), blk, 0, stream>>>(lm_w, lmT, EDIM, VOCAB);
    // lm head: N32000 K1024, 16m x 125n (n-major) = 2000 wg
    gemm_wide_lm<<<dim3(2000, 1), blk, 0, stream>>>(h, lmT, lm_b, out, VOCAB, EDIM, 16, 125);
}